// Round 11
// baseline (332.974 us; speedup 1.0000x reference)
//
#include <hip/hip_runtime.h>

// ---------------------------------------------------------------------------
// GAT edge classifier, MI355X.
//   CSR build: deg hist -> 3-phase parallel scan -> scatter [int atomics only]
//   pack: x -> xh bf16 (A-side); W1,W2 -> transposed bf16 hi/lo splits (merged)
//   GEMM (m97 structure): global_load_lds width=16 staging, BK=64, 2-barrier
//     K-loop, XOR-swizzle both sides. 2-term split (ah*bh + ah*bl = bf16(A)*B).
//     Fused attention epilogue -> as/ad from f32 accs.
//   gather1: 1 wave/node, 16B/lane uint4, half-wave per edge (2 edges/instr),
//     8-edge main loop (4 loads in flight), fused p=exp(lrelu(.)) -> h1 bf16
//   GEMM2 -> xp2b (+attn2 fused); gather2 (8 lanes/row uint4, 8 edges/instr,
//     fused uv = h2 @ Wc halves)
//   classify: out[e] = u[row] + v[col] + bc
// ---------------------------------------------------------------------------

#define NEG 0.2f

typedef __attribute__((ext_vector_type(8))) short bf16x8;
typedef __attribute__((ext_vector_type(4))) float f32x4;

__device__ __forceinline__ unsigned short f2bf(float f) {
    unsigned int u = __float_as_uint(f);
    unsigned int r = (u + 0x7FFFu + ((u >> 16) & 1u)) >> 16;   // RNE
    return (unsigned short)r;
}
__device__ __forceinline__ float bf2f(unsigned short h) {
    return __uint_as_float(((unsigned int)h) << 16);
}
__device__ __forceinline__ float bflo(unsigned int u) { return __uint_as_float(u << 16); }
__device__ __forceinline__ float bfhi(unsigned int u) { return __uint_as_float(u & 0xFFFF0000u); }
__device__ __forceinline__ float lrelu(float x) { return x > 0.f ? x : NEG * x; }

// async global->LDS, 16 bytes per lane. Dest is wave-uniform base + lane*16.
__device__ __forceinline__ void async16(const void* g, void* l) {
    __builtin_amdgcn_global_load_lds(
        (const __attribute__((address_space(1))) unsigned int*)g,
        (__attribute__((address_space(3))) unsigned int*)l, 16, 0, 0);
}

// ------------------------------- CSR build --------------------------------

__global__ __launch_bounds__(256) void k_init(int* deg, int* cur, int n) {
    int i = blockIdx.x * 256 + threadIdx.x;
    if (i < n) { deg[i] = 1; cur[i] = 0; }  // deg starts at 1 for self-loop
}

__global__ __launch_bounds__(256) void k_hist(const int* __restrict__ ei, int* deg, int E) {
    int e = blockIdx.x * 256 + threadIdx.x;
    if (e < E) atomicAdd(&deg[ei[E + e]], 1);   // dst = ei[1][e]
}

__global__ __launch_bounds__(256) void k_bsum(const int* __restrict__ deg, int* __restrict__ bsum, int n) {
    int i = blockIdx.x * 256 + threadIdx.x;
    int v = (i < n) ? deg[i] : 0;
#pragma unroll
    for (int off = 1; off < 64; off <<= 1) v += __shfl_xor(v, off, 64);
    __shared__ int ws[4];
    int wv = threadIdx.x >> 6, l = threadIdx.x & 63;
    if (l == 0) ws[wv] = v;
    __syncthreads();
    if (threadIdx.x == 0) bsum[blockIdx.x] = ws[0] + ws[1] + ws[2] + ws[3];
}

// exclusive scan of bsum[0..nb), nb <= 256; also writes rowptr[n] = total
__global__ __launch_bounds__(256) void k_bscan(const int* __restrict__ bsum, int* __restrict__ boff,
                                               int* __restrict__ rowptr, int nb, int n) {
    __shared__ int s[256];
    int t = threadIdx.x;
    int v = (t < nb) ? bsum[t] : 0;
    s[t] = v;
    __syncthreads();
    for (int off = 1; off < 256; off <<= 1) {
        int u = (t >= off) ? s[t - off] : 0;
        __syncthreads();
        s[t] += u;
        __syncthreads();
    }
    if (t < nb) boff[t] = s[t] - v;
    if (t == nb - 1) rowptr[n] = s[t];
}

__global__ __launch_bounds__(256) void k_rowptr(const int* __restrict__ deg, const int* __restrict__ boff,
                                                int* __restrict__ rowptr, int n) {
    __shared__ int s[256];
    int i = blockIdx.x * 256 + threadIdx.x;
    int t = threadIdx.x;
    int v = (i < n) ? deg[i] : 0;
    s[t] = v;
    __syncthreads();
    for (int off = 1; off < 256; off <<= 1) {
        int u = (t >= off) ? s[t - off] : 0;
        __syncthreads();
        s[t] += u;
        __syncthreads();
    }
    if (i < n) rowptr[i] = boff[blockIdx.x] + s[t] - v;
}

__global__ __launch_bounds__(256) void k_scatter(const int* __restrict__ ei, const int* __restrict__ rowptr,
                                                 int* cur, int* csr_src, int E, int N) {
    int e = blockIdx.x * 256 + threadIdx.x;
    if (e < E) {
        int d = ei[E + e];
        int pos = rowptr[d] + atomicAdd(&cur[d], 1);
        csr_src[pos] = ei[e];
    } else if (e < E + N) {
        int i = e - E;  // self loop
        int pos = rowptr[i] + atomicAdd(&cur[i], 1);
        csr_src[pos] = i;
    }
}

// ------------------------------- packing ----------------------------------

// fp32 -> bf16 (A-side only needs hi; 2-term split keeps B in hi/lo)
__global__ __launch_bounds__(256) void k_pack_hi(const float* __restrict__ src,
                                                 unsigned short* __restrict__ hi, long n4) {
    long i = (long)blockIdx.x * 256 + threadIdx.x;
    long stride = (long)gridDim.x * 256;
    for (; i < n4; i += stride) {
        float4 v = ((const float4*)src)[i];
        ((ushort4*)hi)[i] = make_ushort4(f2bf(v.x), f2bf(v.y), f2bf(v.z), f2bf(v.w));
    }
}

// W1 [256,256] and W2 [256,64] -> transposed hi/lo bf16, one dispatch
__global__ __launch_bounds__(256) void k_pack_w2(const float* __restrict__ W1,
                                                 const float* __restrict__ W2,
                                                 unsigned short* __restrict__ W1hT,
                                                 unsigned short* __restrict__ W1lT,
                                                 unsigned short* __restrict__ W2hT,
                                                 unsigned short* __restrict__ W2lT) {
    int t = blockIdx.x * 256 + threadIdx.x;
    if (t < 256 * 256) {
        int n = t >> 8, k = t & 255;        // [N=256,K=256]
        float v = W1[k * 256 + n];
        unsigned short h = f2bf(v);
        W1hT[t] = h;
        W1lT[t] = f2bf(v - bf2f(h));
    } else {
        int t2 = t - 256 * 256;
        if (t2 < 64 * 256) {
            int n = t2 >> 8, k = t2 & 255;  // [N=64,K=256]
            float v = W2[k * 64 + n];
            unsigned short h = f2bf(v);
            W2hT[t2] = h;
            W2lT[t2] = f2bf(v - bf2f(h));
        }
    }
}

// ------------------------------- MFMA GEMM (LDS, m97 structure) -----------
// C[M,N] = bf16(A)[M,K] @ B[K,N] (B as hi/lo bf16 [N,K], 2-term).
// Fused attn epilogue: wave owns one head's 64 cols -> as/ad row dots.
template<int WGM, int WGN>
__global__ __launch_bounds__(256, 2) void k_gemm_lds(const unsigned short* __restrict__ Ah,
                                                     const unsigned short* __restrict__ BhT,
                                                     const unsigned short* __restrict__ BlT,
                                                     unsigned short* __restrict__ Cb, int M, int N, int K,
                                                     const float* __restrict__ att_s,
                                                     const float* __restrict__ att_d,
                                                     float* __restrict__ as, float* __restrict__ ad, int H) {
    constexpr int BM = WGM * 64, BN = WGN * 64;
    __shared__ char lds[BM * 128 + BN * 256];      // Ah | Bh | Bl, rows*128B
    char* LAh = lds;
    char* LBh = lds + BM * 128;
    char* LBl = lds + BM * 128 + BN * 128;

    const int t = threadIdx.x, wv = t >> 6, l = t & 63;
    const int r = l & 15, hk = l >> 4;
    const int m0 = blockIdx.x * BM;
    const int n0 = blockIdx.y * BN;
    const int wr = wv / WGN, wc = wv % WGN;
    const int wrow0 = wr * 64, wcol0 = wc * 64;

    f32x4 acc[4][4];
#pragma unroll
    for (int i = 0; i < 4; i++)
#pragma unroll
        for (int j = 0; j < 4; j++) acc[i][j] = f32x4{0, 0, 0, 0};

    const int lrow8 = l >> 3;                       // 0..7
    const int cbs = ((l & 7) ^ lrow8) << 4;         // inverse-swizzled src col byte
    const size_t K2 = (size_t)K * 2;
    const int NCH = K >> 6;

    for (int c = 0; c < NCH; ++c) {
        const int kk2 = c * 128;
        {
            const int SA = BM / 8;
            for (int i = wv; i < SA; i += 4) {
                int row = i * 8 + lrow8;
                size_t go = (size_t)(m0 + row) * K2 + kk2 + cbs;
                async16((const char*)Ah + go, LAh + i * 1024);
            }
            const int SB = BN / 8;
            for (int i = wv; i < SB; i += 4) {
                int row = i * 8 + lrow8;
                size_t go = (size_t)(n0 + row) * K2 + kk2 + cbs;
                async16((const char*)BhT + go, LBh + i * 1024);
                async16((const char*)BlT + go, LBl + i * 1024);
            }
        }
        __syncthreads();
#pragma unroll
        for (int ks = 0; ks < 2; ++ks) {
            const int cb = ks * 64 + hk * 16;
            bf16x8 a_h[4], b_h[4], b_l[4];
#pragma unroll
            for (int fm = 0; fm < 4; ++fm) {
                int row = wrow0 + fm * 16 + r;
                int ad_ = row * 128 + (cb ^ ((row & 7) << 4));
                a_h[fm] = *(const bf16x8*)(LAh + ad_);
            }
#pragma unroll
            for (int fn = 0; fn < 4; ++fn) {
                int row = wcol0 + fn * 16 + r;
                int ad_ = row * 128 + (cb ^ ((row & 7) << 4));
                b_h[fn] = *(const bf16x8*)(LBh + ad_);
                b_l[fn] = *(const bf16x8*)(LBl + ad_);
            }
#pragma unroll
            for (int fm = 0; fm < 4; ++fm)
#pragma unroll
                for (int fn = 0; fn < 4; ++fn) {
                    acc[fm][fn] = __builtin_amdgcn_mfma_f32_16x16x32_bf16(a_h[fm], b_h[fn], acc[fm][fn], 0, 0, 0);
                    acc[fm][fn] = __builtin_amdgcn_mfma_f32_16x16x32_bf16(a_h[fm], b_l[fn], acc[fm][fn], 0, 0, 0);
                }
        }
        if (c + 1 < NCH) __syncthreads();
    }

    // ---- C write (C/D frag: col=lane&15, row=(lane>>4)*4+j) ----
#pragma unroll
    for (int fm = 0; fm < 4; ++fm)
#pragma unroll
        for (int fn = 0; fn < 4; ++fn)
#pragma unroll
            for (int j = 0; j < 4; ++j) {
                int m = m0 + wrow0 + fm * 16 + hk * 4 + j;
                if (m < M) Cb[(size_t)m * N + n0 + wcol0 + fn * 16 + r] = f2bf(acc[fm][fn][j]);
            }

    // ---- fused attention dots for this wave's head (from f32 accs) ----
    {
        int head = (n0 + wcol0) >> 6;
        float satt[4], datt[4];
#pragma unroll
        for (int fn = 0; fn < 4; ++fn) {
            satt[fn] = att_s[head * 64 + fn * 16 + r];
            datt[fn] = att_d[head * 64 + fn * 16 + r];
        }
#pragma unroll
        for (int fm = 0; fm < 4; ++fm)
#pragma unroll
            for (int j = 0; j < 4; ++j) {
                float ps = 0.f, pd = 0.f;
#pragma unroll
                for (int fn = 0; fn < 4; ++fn) {
                    ps += satt[fn] * acc[fm][fn][j];
                    pd += datt[fn] * acc[fm][fn][j];
                }
#pragma unroll
                for (int off = 1; off <= 8; off <<= 1) {
                    ps += __shfl_xor(ps, off, 64);
                    pd += __shfl_xor(pd, off, 64);
                }
                if (r == 0) {
                    int m = m0 + wrow0 + fm * 16 + hk * 4 + j;
                    if (m < M) { as[m * H + head] = ps; ad[m * H + head] = pd; }
                }
            }
    }
}

// ------------------------------- gathers ----------------------------------

// gather layer 1: 1 wave/node. Lane layout: half=lane>>5 picks the edge of a
// pair, q=lane&31 owns cols q*8..q*8+7 (uint4 = 16B), head h=q>>3.
// One VMEM instr covers 2 edges; 8-edge main loop = 4 loads in flight.
__global__ __launch_bounds__(256) void k_gather1(const unsigned short* __restrict__ xpb,
                                                 const float* __restrict__ as, const float* __restrict__ ad,
                                                 const int* __restrict__ rowptr, const int* __restrict__ csr_src,
                                                 const float* __restrict__ b1,
                                                 unsigned short* __restrict__ h1h, int M) {
    int wv = threadIdx.x >> 6, lane = threadIdx.x & 63;
    int n = blockIdx.x * 4 + wv;
    if (n >= M) return;
    int half = lane >> 5;
    int q = lane & 31;
    int h = q >> 3;
    float adv = ad[n * 4 + h];
    int start = rowptr[n], end = rowptr[n + 1];
    float acc[8] = {0.f, 0.f, 0.f, 0.f, 0.f, 0.f, 0.f, 0.f};
    float den = 0.f;

    auto edge = [&](int s, uint4 v) {
        float p = __expf(lrelu(as[s * 4 + h] + adv));
        den += p;
        acc[0] += p * bflo(v.x); acc[1] += p * bfhi(v.x);
        acc[2] += p * bflo(v.y); acc[3] += p * bfhi(v.y);
        acc[4] += p * bflo(v.z); acc[5] += p * bfhi(v.z);
        acc[6] += p * bflo(v.w); acc[7] += p * bfhi(v.w);
    };

    int e = start;
    for (; e + 7 < end; e += 8) {
        int sa = csr_src[e + half];
        int sb = csr_src[e + 2 + half];
        int sc = csr_src[e + 4 + half];
        int sd = csr_src[e + 6 + half];
        uint4 va = *(const uint4*)(xpb + (size_t)sa * 256 + q * 8);
        uint4 vb = *(const uint4*)(xpb + (size_t)sb * 256 + q * 8);
        uint4 vc = *(const uint4*)(xpb + (size_t)sc * 256 + q * 8);
        uint4 vd = *(const uint4*)(xpb + (size_t)sd * 256 + q * 8);
        edge(sa, va); edge(sb, vb); edge(sc, vc); edge(sd, vd);
    }
    if (e + 3 < end) {
        int sa = csr_src[e + half];
        int sb = csr_src[e + 2 + half];
        uint4 va = *(const uint4*)(xpb + (size_t)sa * 256 + q * 8);
        uint4 vb = *(const uint4*)(xpb + (size_t)sb * 256 + q * 8);
        edge(sa, va); edge(sb, vb);
        e += 4;
    }
    if (e + 1 < end) {
        int sa = csr_src[e + half];
        uint4 va = *(const uint4*)(xpb + (size_t)sa * 256 + q * 8);
        edge(sa, va);
        e += 2;
    }
    if (e < end && half == 0) {
        int sa = csr_src[e];
        uint4 va = *(const uint4*)(xpb + (size_t)sa * 256 + q * 8);
        edge(sa, va);
    }

    // combine the two halves
#pragma unroll
    for (int j = 0; j < 8; j++) acc[j] += __shfl_xor(acc[j], 32, 64);
    den += __shfl_xor(den, 32, 64);

    float dinv = 1.f / (den + 1e-16f);
    float4 b0 = *(const float4*)(b1 + q * 8);
    float4 b4 = *(const float4*)(b1 + q * 8 + 4);
    float o0 = fmaxf(acc[0] * dinv + b0.x, 0.f);
    float o1 = fmaxf(acc[1] * dinv + b0.y, 0.f);
    float o2 = fmaxf(acc[2] * dinv + b0.z, 0.f);
    float o3 = fmaxf(acc[3] * dinv + b0.w, 0.f);
    float o4 = fmaxf(acc[4] * dinv + b4.x, 0.f);
    float o5 = fmaxf(acc[5] * dinv + b4.y, 0.f);
    float o6 = fmaxf(acc[6] * dinv + b4.z, 0.f);
    float o7 = fmaxf(acc[7] * dinv + b4.w, 0.f);
    if (half == 0) {
        uint4 Hv;
        Hv.x = (unsigned)f2bf(o0) | ((unsigned)f2bf(o1) << 16);
        Hv.y = (unsigned)f2bf(o2) | ((unsigned)f2bf(o3) << 16);
        Hv.z = (unsigned)f2bf(o4) | ((unsigned)f2bf(o5) << 16);
        Hv.w = (unsigned)f2bf(o6) | ((unsigned)f2bf(o7) << 16);
        *(uint4*)(h1h + (size_t)n * 256 + q * 8) = Hv;
    }
}

// gather layer 2 (1 head, C=64): 1 wave/node, 8 edge-groups of 8 lanes,
// lane q=lane&7 owns cols q*8..q*8+7 (uint4). Fused uv = (h2+b2) . Wc halves.
__global__ __launch_bounds__(256) void k_gather2(const unsigned short* __restrict__ xp2b,
                                                 const float* __restrict__ as, const float* __restrict__ ad,
                                                 const int* __restrict__ rowptr, const int* __restrict__ csr_src,
                                                 const float* __restrict__ b2, const float* __restrict__ Wc,
                                                 float* __restrict__ uv, int M) {
    int wv = threadIdx.x >> 6, lane = threadIdx.x & 63;
    int n = blockIdx.x * 4 + wv;
    if (n >= M) return;
    int g = lane >> 3, q = lane & 7;
    float adv = ad[n];
    int start = rowptr[n], end = rowptr[n + 1];
    float acc[8] = {0.f, 0.f, 0.f, 0.f, 0.f, 0.f, 0.f, 0.f};
    float den = 0.f;
    for (int e = start; e < end; e += 8) {
        int ee = e + g;
        bool ok = ee < end;
        int s = csr_src[ok ? ee : start];
        uint4 v = *(const uint4*)(xp2b + (size_t)s * 64 + q * 8);
        float pw = ok ? __expf(lrelu(as[s] + adv)) : 0.f;
        den += pw;
        acc[0] += pw * bflo(v.x); acc[1] += pw * bfhi(v.x);
        acc[2] += pw * bflo(v.y); acc[3] += pw * bfhi(v.y);
        acc[4] += pw * bflo(v.z); acc[5] += pw * bfhi(v.z);
        acc[6] += pw * bflo(v.w); acc[7] += pw * bfhi(v.w);
    }
#pragma unroll
    for (int j = 0; j < 8; j++) {
        acc[j] += __shfl_xor(acc[j], 8, 64);
        acc[j] += __shfl_xor(acc[j], 16, 64);
        acc[j] += __shfl_xor(acc[j], 32, 64);
    }
    den += __shfl_xor(den, 8, 64);
    den += __shfl_xor(den, 16, 64);
    den += __shfl_xor(den, 32, 64);
    float dinv = 1.f / (den + 1e-16f);
    float pr[8] = {0.f, 0.f, 0.f, 0.f, 0.f, 0.f, 0.f, 0.f};
#pragma unroll
    for (int j = 0; j < 8; j++) {
        int c = q * 8 + j;
        float val = acc[j] * dinv + b2[c];
#pragma unroll
        for (int k = 0; k < 4; k++) {
            pr[k]     += val * Wc[c * 4 + k];
            pr[4 + k] += val * Wc[(64 + c) * 4 + k];
        }
    }
#pragma unroll
    for (int off = 1; off <= 4; off <<= 1)
#pragma unroll
        for (int j = 0; j < 8; j++) pr[j] += __shfl_xor(pr[j], off, 64);
    if (lane == 0) {
        float4* o = (float4*)(uv + (size_t)n * 8);
        o[0] = make_float4(pr[0], pr[1], pr[2], pr[3]);
        o[1] = make_float4(pr[4], pr[5], pr[6], pr[7]);
    }
}

__global__ __launch_bounds__(256) void k_classify(const int* __restrict__ ei, const float* __restrict__ uv,
                                                  const float* __restrict__ bc, float* __restrict__ out, int E) {
    int e = blockIdx.x * 256 + threadIdx.x;
    if (e >= E) return;
    int r = ei[e];
    int c = ei[E + e];
    float4 u = *(const float4*)(uv + (size_t)r * 8);
    float4 v = *(const float4*)(uv + (size_t)c * 8 + 4);
    float4 o;
    o.x = u.x + v.x + bc[0];
    o.y = u.y + v.y + bc[1];
    o.z = u.z + v.z + bc[2];
    o.w = u.w + v.w + bc[3];
    *(float4*)(out + (size_t)e * 4) = o;
}

// ---------------------------------------------------------------------------

extern "C" void kernel_launch(void* const* d_in, const int* in_sizes, int n_in,
                              void* d_out, int out_size, void* d_ws, size_t ws_size,
                              hipStream_t stream) {
    const float* x    = (const float*)d_in[0];
    const int*   ei   = (const int*)d_in[1];
    // d_in[2] = w (edge weights) ignored by reference
    const float* W1   = (const float*)d_in[3];
    const float* atS1 = (const float*)d_in[4];
    const float* atD1 = (const float*)d_in[5];
    const float* b1   = (const float*)d_in[6];
    const float* W2   = (const float*)d_in[7];
    const float* atS2 = (const float*)d_in[8];
    const float* atD2 = (const float*)d_in[9];
    const float* b2   = (const float*)d_in[10];
    const float* Wc   = (const float*)d_in[11];
    const float* bc   = (const float*)d_in[12];
    float* out = (float*)d_out;

    const int Nn = in_sizes[0] / 256;   // nodes
    const int E = in_sizes[1] / 2;
    const int Etot = E + Nn;
    const int NB = (Nn + 255) / 256;    // scan blocks

    char* w = (char*)d_ws;
    size_t off = 0;
    auto alloc = [&](size_t b) { size_t o = off; off = (o + b + 255) & ~(size_t)255; return o; };
    size_t oXH  = alloc((size_t)Nn * 256 * 2);   // x bf16; later h1h
    size_t oXPB = alloc((size_t)Nn * 256 * 2);   // xp bf16; later xp2b|uv
    size_t oAS1 = alloc((size_t)Nn * 4 * 4);
    size_t oAD1 = alloc((size_t)Nn * 4 * 4);
    size_t oDEG = alloc((size_t)Nn * 4);
    size_t oCUR = alloc((size_t)Nn * 4);
    size_t oRP  = alloc((size_t)(Nn + 1) * 4);
    size_t oCSR = alloc((size_t)Etot * 4);
    size_t oW1H = alloc((size_t)256 * 256 * 2);
    size_t oW1L = alloc((size_t)256 * 256 * 2);
    size_t oW2H = alloc((size_t)256 * 64 * 2);
    size_t oW2L = alloc((size_t)256 * 64 * 2);
    size_t oBS  = alloc((size_t)NB * 4);
    size_t oBO  = alloc((size_t)NB * 4);
    (void)ws_size;

    unsigned short* xh   = (unsigned short*)(w + oXH);
    unsigned short* h1h  = (unsigned short*)(w + oXH);   // alias: xh dead after gemm1
    unsigned short* xpb  = (unsigned short*)(w + oXPB);
    unsigned short* xp2b = (unsigned short*)(w + oXPB);  // alias: xpb dead after gather1
    float* uv  = (float*)(w + oXPB + (size_t)Nn * 64 * 2 + 256);
    uv = (float*)(((uintptr_t)uv + 255) & ~(uintptr_t)255);
    float* as1 = (float*)(w + oAS1);
    float* ad1 = (float*)(w + oAD1);
    float* as2 = (float*)(w + oAS1);                     // alias: as1 dead after gather1
    float* ad2 = (float*)(w + oAD1);
    int* deg    = (int*)(w + oDEG);
    int* cur    = (int*)(w + oCUR);
    int* rowptr = (int*)(w + oRP);
    int* csr    = (int*)(w + oCSR);
    int* bsum   = (int*)(w + oBS);
    int* boff   = (int*)(w + oBO);
    unsigned short* W1hT = (unsigned short*)(w + oW1H);
    unsigned short* W1lT = (unsigned short*)(w + oW1L);
    unsigned short* W2hT = (unsigned short*)(w + oW2H);
    unsigned short* W2lT = (unsigned short*)(w + oW2L);

    // CSR build (parallel scan)
    k_init<<<NB, 256, 0, stream>>>(deg, cur, Nn);
    k_hist<<<(E + 255) / 256, 256, 0, stream>>>(ei, deg, E);
    k_bsum<<<NB, 256, 0, stream>>>(deg, bsum, Nn);
    k_bscan<<<1, 256, 0, stream>>>(bsum, boff, rowptr, NB, Nn);
    k_rowptr<<<NB, 256, 0, stream>>>(deg, boff, rowptr, Nn);
    k_scatter<<<(Etot + 255) / 256, 256, 0, stream>>>(ei, rowptr, cur, csr, E, Nn);

    // packing
    k_pack_hi<<<2048, 256, 0, stream>>>(x, xh, (long)Nn * 64);
    k_pack_w2<<<(256 * 256 + 64 * 256 + 255) / 256, 256, 0, stream>>>(W1, W2, W1hT, W1lT, W2hT, W2lT);

    // Layer 1: 128x128 tile (WGM=2, WGN=2), grid.y = 2; attn fused
    {
        dim3 g((Nn + 127) / 128, 2);
        k_gemm_lds<2, 2><<<g, 256, 0, stream>>>(xh, W1hT, W1lT, xpb, Nn, 256, 256,
                                                atS1, atD1, as1, ad1, 4);
    }
    k_gather1<<<(Nn + 3) / 4, 256, 0, stream>>>(xpb, as1, ad1, rowptr, csr, b1, h1h, Nn);

    // Layer 2: 256x64 tile (WGM=4, WGN=1), grid.y = 1; attn fused
    {
        dim3 g((Nn + 255) / 256, 1);
        k_gemm_lds<4, 1><<<g, 256, 0, stream>>>(h1h, W2hT, W2lT, xp2b, Nn, 64, 256,
                                                atS2, atD2, as2, ad2, 1);
    }
    k_gather2<<<(Nn + 3) / 4, 256, 0, stream>>>(xp2b, as2, ad2, rowptr, csr, b2, Wc, uv, Nn);

    // Edge classifier
    k_classify<<<(E + 255) / 256, 256, 0, stream>>>(ei, uv, bc, out, E);
}

// Round 12
// 281.981 us; speedup vs baseline: 1.1808x; 1.1808x over previous
//
#include <hip/hip_runtime.h>

// ---------------------------------------------------------------------------
// GAT edge classifier, MI355X.
//   CSR build: deg hist -> 3-phase parallel scan -> scatter [int atomics only]
//   pack: x -> xh bf16 (A-side); W1,W2 -> transposed bf16 hi/lo splits (merged)
//   GEMM (m97 structure): global_load_lds width=16 staging, BK=64, 2-barrier
//     K-loop, XOR-swizzle both sides. 2-term split (ah*bh + ah*bl = bf16(A)*B).
//     Fused attention epilogue -> as/ad from f32 accs.
//   gather1: 1 wave/node, 16B/lane uint4, half-wave per edge (2 edges/instr),
//     8-edge main loop (4 loads in flight), fused p=exp(lrelu(.)) -> h1 bf16
//   GEMM2 -> xp2b (+attn2 fused)
//   gather2: ROUND-10 SHAPE (r11's 8-lane/uint4 form was a 3x regression:
//     VALU 17%, all pipes idle, ~26K cyc/wave -- reverted to measured-good
//     16-lane groups, uint2, 4 edge-groups, fused uv = h2 @ Wc halves)
//   classify: out[e] = u[row] + v[col] + bc
// ---------------------------------------------------------------------------

#define NEG 0.2f

typedef __attribute__((ext_vector_type(8))) short bf16x8;
typedef __attribute__((ext_vector_type(4))) float f32x4;

__device__ __forceinline__ unsigned short f2bf(float f) {
    unsigned int u = __float_as_uint(f);
    unsigned int r = (u + 0x7FFFu + ((u >> 16) & 1u)) >> 16;   // RNE
    return (unsigned short)r;
}
__device__ __forceinline__ float bf2f(unsigned short h) {
    return __uint_as_float(((unsigned int)h) << 16);
}
__device__ __forceinline__ float bflo(unsigned int u) { return __uint_as_float(u << 16); }
__device__ __forceinline__ float bfhi(unsigned int u) { return __uint_as_float(u & 0xFFFF0000u); }
__device__ __forceinline__ float lrelu(float x) { return x > 0.f ? x : NEG * x; }

// async global->LDS, 16 bytes per lane. Dest is wave-uniform base + lane*16.
__device__ __forceinline__ void async16(const void* g, void* l) {
    __builtin_amdgcn_global_load_lds(
        (const __attribute__((address_space(1))) unsigned int*)g,
        (__attribute__((address_space(3))) unsigned int*)l, 16, 0, 0);
}

// ------------------------------- CSR build --------------------------------

__global__ __launch_bounds__(256) void k_init(int* deg, int* cur, int n) {
    int i = blockIdx.x * 256 + threadIdx.x;
    if (i < n) { deg[i] = 1; cur[i] = 0; }  // deg starts at 1 for self-loop
}

__global__ __launch_bounds__(256) void k_hist(const int* __restrict__ ei, int* deg, int E) {
    int e = blockIdx.x * 256 + threadIdx.x;
    if (e < E) atomicAdd(&deg[ei[E + e]], 1);   // dst = ei[1][e]
}

__global__ __launch_bounds__(256) void k_bsum(const int* __restrict__ deg, int* __restrict__ bsum, int n) {
    int i = blockIdx.x * 256 + threadIdx.x;
    int v = (i < n) ? deg[i] : 0;
#pragma unroll
    for (int off = 1; off < 64; off <<= 1) v += __shfl_xor(v, off, 64);
    __shared__ int ws[4];
    int wv = threadIdx.x >> 6, l = threadIdx.x & 63;
    if (l == 0) ws[wv] = v;
    __syncthreads();
    if (threadIdx.x == 0) bsum[blockIdx.x] = ws[0] + ws[1] + ws[2] + ws[3];
}

// exclusive scan of bsum[0..nb), nb <= 256; also writes rowptr[n] = total
__global__ __launch_bounds__(256) void k_bscan(const int* __restrict__ bsum, int* __restrict__ boff,
                                               int* __restrict__ rowptr, int nb, int n) {
    __shared__ int s[256];
    int t = threadIdx.x;
    int v = (t < nb) ? bsum[t] : 0;
    s[t] = v;
    __syncthreads();
    for (int off = 1; off < 256; off <<= 1) {
        int u = (t >= off) ? s[t - off] : 0;
        __syncthreads();
        s[t] += u;
        __syncthreads();
    }
    if (t < nb) boff[t] = s[t] - v;
    if (t == nb - 1) rowptr[n] = s[t];
}

__global__ __launch_bounds__(256) void k_rowptr(const int* __restrict__ deg, const int* __restrict__ boff,
                                                int* __restrict__ rowptr, int n) {
    __shared__ int s[256];
    int i = blockIdx.x * 256 + threadIdx.x;
    int t = threadIdx.x;
    int v = (i < n) ? deg[i] : 0;
    s[t] = v;
    __syncthreads();
    for (int off = 1; off < 256; off <<= 1) {
        int u = (t >= off) ? s[t - off] : 0;
        __syncthreads();
        s[t] += u;
        __syncthreads();
    }
    if (i < n) rowptr[i] = boff[blockIdx.x] + s[t] - v;
}

__global__ __launch_bounds__(256) void k_scatter(const int* __restrict__ ei, const int* __restrict__ rowptr,
                                                 int* cur, int* csr_src, int E, int N) {
    int e = blockIdx.x * 256 + threadIdx.x;
    if (e < E) {
        int d = ei[E + e];
        int pos = rowptr[d] + atomicAdd(&cur[d], 1);
        csr_src[pos] = ei[e];
    } else if (e < E + N) {
        int i = e - E;  // self loop
        int pos = rowptr[i] + atomicAdd(&cur[i], 1);
        csr_src[pos] = i;
    }
}

// ------------------------------- packing ----------------------------------

// fp32 -> bf16 (A-side only needs hi; 2-term split keeps B in hi/lo)
__global__ __launch_bounds__(256) void k_pack_hi(const float* __restrict__ src,
                                                 unsigned short* __restrict__ hi, long n4) {
    long i = (long)blockIdx.x * 256 + threadIdx.x;
    long stride = (long)gridDim.x * 256;
    for (; i < n4; i += stride) {
        float4 v = ((const float4*)src)[i];
        ((ushort4*)hi)[i] = make_ushort4(f2bf(v.x), f2bf(v.y), f2bf(v.z), f2bf(v.w));
    }
}

// W1 [256,256] and W2 [256,64] -> transposed hi/lo bf16, one dispatch
__global__ __launch_bounds__(256) void k_pack_w2(const float* __restrict__ W1,
                                                 const float* __restrict__ W2,
                                                 unsigned short* __restrict__ W1hT,
                                                 unsigned short* __restrict__ W1lT,
                                                 unsigned short* __restrict__ W2hT,
                                                 unsigned short* __restrict__ W2lT) {
    int t = blockIdx.x * 256 + threadIdx.x;
    if (t < 256 * 256) {
        int n = t >> 8, k = t & 255;        // [N=256,K=256]
        float v = W1[k * 256 + n];
        unsigned short h = f2bf(v);
        W1hT[t] = h;
        W1lT[t] = f2bf(v - bf2f(h));
    } else {
        int t2 = t - 256 * 256;
        if (t2 < 64 * 256) {
            int n = t2 >> 8, k = t2 & 255;  // [N=64,K=256]
            float v = W2[k * 64 + n];
            unsigned short h = f2bf(v);
            W2hT[t2] = h;
            W2lT[t2] = f2bf(v - bf2f(h));
        }
    }
}

// ------------------------------- MFMA GEMM (LDS, m97 structure) -----------
// C[M,N] = bf16(A)[M,K] @ B[K,N] (B as hi/lo bf16 [N,K], 2-term).
// Fused attn epilogue: wave owns one head's 64 cols -> as/ad row dots.
template<int WGM, int WGN>
__global__ __launch_bounds__(256, 2) void k_gemm_lds(const unsigned short* __restrict__ Ah,
                                                     const unsigned short* __restrict__ BhT,
                                                     const unsigned short* __restrict__ BlT,
                                                     unsigned short* __restrict__ Cb, int M, int N, int K,
                                                     const float* __restrict__ att_s,
                                                     const float* __restrict__ att_d,
                                                     float* __restrict__ as, float* __restrict__ ad, int H) {
    constexpr int BM = WGM * 64, BN = WGN * 64;
    __shared__ char lds[BM * 128 + BN * 256];      // Ah | Bh | Bl, rows*128B
    char* LAh = lds;
    char* LBh = lds + BM * 128;
    char* LBl = lds + BM * 128 + BN * 128;

    const int t = threadIdx.x, wv = t >> 6, l = t & 63;
    const int r = l & 15, hk = l >> 4;
    const int m0 = blockIdx.x * BM;
    const int n0 = blockIdx.y * BN;
    const int wr = wv / WGN, wc = wv % WGN;
    const int wrow0 = wr * 64, wcol0 = wc * 64;

    f32x4 acc[4][4];
#pragma unroll
    for (int i = 0; i < 4; i++)
#pragma unroll
        for (int j = 0; j < 4; j++) acc[i][j] = f32x4{0, 0, 0, 0};

    const int lrow8 = l >> 3;                       // 0..7
    const int cbs = ((l & 7) ^ lrow8) << 4;         // inverse-swizzled src col byte
    const size_t K2 = (size_t)K * 2;
    const int NCH = K >> 6;

    for (int c = 0; c < NCH; ++c) {
        const int kk2 = c * 128;
        {
            const int SA = BM / 8;
            for (int i = wv; i < SA; i += 4) {
                int row = i * 8 + lrow8;
                size_t go = (size_t)(m0 + row) * K2 + kk2 + cbs;
                async16((const char*)Ah + go, LAh + i * 1024);
            }
            const int SB = BN / 8;
            for (int i = wv; i < SB; i += 4) {
                int row = i * 8 + lrow8;
                size_t go = (size_t)(n0 + row) * K2 + kk2 + cbs;
                async16((const char*)BhT + go, LBh + i * 1024);
                async16((const char*)BlT + go, LBl + i * 1024);
            }
        }
        __syncthreads();
#pragma unroll
        for (int ks = 0; ks < 2; ++ks) {
            const int cb = ks * 64 + hk * 16;
            bf16x8 a_h[4], b_h[4], b_l[4];
#pragma unroll
            for (int fm = 0; fm < 4; ++fm) {
                int row = wrow0 + fm * 16 + r;
                int ad_ = row * 128 + (cb ^ ((row & 7) << 4));
                a_h[fm] = *(const bf16x8*)(LAh + ad_);
            }
#pragma unroll
            for (int fn = 0; fn < 4; ++fn) {
                int row = wcol0 + fn * 16 + r;
                int ad_ = row * 128 + (cb ^ ((row & 7) << 4));
                b_h[fn] = *(const bf16x8*)(LBh + ad_);
                b_l[fn] = *(const bf16x8*)(LBl + ad_);
            }
#pragma unroll
            for (int fm = 0; fm < 4; ++fm)
#pragma unroll
                for (int fn = 0; fn < 4; ++fn) {
                    acc[fm][fn] = __builtin_amdgcn_mfma_f32_16x16x32_bf16(a_h[fm], b_h[fn], acc[fm][fn], 0, 0, 0);
                    acc[fm][fn] = __builtin_amdgcn_mfma_f32_16x16x32_bf16(a_h[fm], b_l[fn], acc[fm][fn], 0, 0, 0);
                }
        }
        if (c + 1 < NCH) __syncthreads();
    }

    // ---- C write (C/D frag: col=lane&15, row=(lane>>4)*4+j) ----
#pragma unroll
    for (int fm = 0; fm < 4; ++fm)
#pragma unroll
        for (int fn = 0; fn < 4; ++fn)
#pragma unroll
            for (int j = 0; j < 4; ++j) {
                int m = m0 + wrow0 + fm * 16 + hk * 4 + j;
                if (m < M) Cb[(size_t)m * N + n0 + wcol0 + fn * 16 + r] = f2bf(acc[fm][fn][j]);
            }

    // ---- fused attention dots for this wave's head (from f32 accs) ----
    {
        int head = (n0 + wcol0) >> 6;
        float satt[4], datt[4];
#pragma unroll
        for (int fn = 0; fn < 4; ++fn) {
            satt[fn] = att_s[head * 64 + fn * 16 + r];
            datt[fn] = att_d[head * 64 + fn * 16 + r];
        }
#pragma unroll
        for (int fm = 0; fm < 4; ++fm)
#pragma unroll
            for (int j = 0; j < 4; ++j) {
                float ps = 0.f, pd = 0.f;
#pragma unroll
                for (int fn = 0; fn < 4; ++fn) {
                    ps += satt[fn] * acc[fm][fn][j];
                    pd += datt[fn] * acc[fm][fn][j];
                }
#pragma unroll
                for (int off = 1; off <= 8; off <<= 1) {
                    ps += __shfl_xor(ps, off, 64);
                    pd += __shfl_xor(pd, off, 64);
                }
                if (r == 0) {
                    int m = m0 + wrow0 + fm * 16 + hk * 4 + j;
                    if (m < M) { as[m * H + head] = ps; ad[m * H + head] = pd; }
                }
            }
    }
}

// ------------------------------- gathers ----------------------------------

// gather layer 1: 1 wave/node. Lane layout: half=lane>>5 picks the edge of a
// pair, q=lane&31 owns cols q*8..q*8+7 (uint4 = 16B), head h=q>>3.
// One VMEM instr covers 2 edges; 8-edge main loop = 4 loads in flight.
__global__ __launch_bounds__(256) void k_gather1(const unsigned short* __restrict__ xpb,
                                                 const float* __restrict__ as, const float* __restrict__ ad,
                                                 const int* __restrict__ rowptr, const int* __restrict__ csr_src,
                                                 const float* __restrict__ b1,
                                                 unsigned short* __restrict__ h1h, int M) {
    int wv = threadIdx.x >> 6, lane = threadIdx.x & 63;
    int n = blockIdx.x * 4 + wv;
    if (n >= M) return;
    int half = lane >> 5;
    int q = lane & 31;
    int h = q >> 3;
    float adv = ad[n * 4 + h];
    int start = rowptr[n], end = rowptr[n + 1];
    float acc[8] = {0.f, 0.f, 0.f, 0.f, 0.f, 0.f, 0.f, 0.f};
    float den = 0.f;

    auto edge = [&](int s, uint4 v) {
        float p = __expf(lrelu(as[s * 4 + h] + adv));
        den += p;
        acc[0] += p * bflo(v.x); acc[1] += p * bfhi(v.x);
        acc[2] += p * bflo(v.y); acc[3] += p * bfhi(v.y);
        acc[4] += p * bflo(v.z); acc[5] += p * bfhi(v.z);
        acc[6] += p * bflo(v.w); acc[7] += p * bfhi(v.w);
    };

    int e = start;
    for (; e + 7 < end; e += 8) {
        int sa = csr_src[e + half];
        int sb = csr_src[e + 2 + half];
        int sc = csr_src[e + 4 + half];
        int sd = csr_src[e + 6 + half];
        uint4 va = *(const uint4*)(xpb + (size_t)sa * 256 + q * 8);
        uint4 vb = *(const uint4*)(xpb + (size_t)sb * 256 + q * 8);
        uint4 vc = *(const uint4*)(xpb + (size_t)sc * 256 + q * 8);
        uint4 vd = *(const uint4*)(xpb + (size_t)sd * 256 + q * 8);
        edge(sa, va); edge(sb, vb); edge(sc, vc); edge(sd, vd);
    }
    if (e + 3 < end) {
        int sa = csr_src[e + half];
        int sb = csr_src[e + 2 + half];
        uint4 va = *(const uint4*)(xpb + (size_t)sa * 256 + q * 8);
        uint4 vb = *(const uint4*)(xpb + (size_t)sb * 256 + q * 8);
        edge(sa, va); edge(sb, vb);
        e += 4;
    }
    if (e + 1 < end) {
        int sa = csr_src[e + half];
        uint4 va = *(const uint4*)(xpb + (size_t)sa * 256 + q * 8);
        edge(sa, va);
        e += 2;
    }
    if (e < end && half == 0) {
        int sa = csr_src[e];
        uint4 va = *(const uint4*)(xpb + (size_t)sa * 256 + q * 8);
        edge(sa, va);
    }

    // combine the two halves
#pragma unroll
    for (int j = 0; j < 8; j++) acc[j] += __shfl_xor(acc[j], 32, 64);
    den += __shfl_xor(den, 32, 64);

    float dinv = 1.f / (den + 1e-16f);
    float4 b0 = *(const float4*)(b1 + q * 8);
    float4 b4 = *(const float4*)(b1 + q * 8 + 4);
    float o0 = fmaxf(acc[0] * dinv + b0.x, 0.f);
    float o1 = fmaxf(acc[1] * dinv + b0.y, 0.f);
    float o2 = fmaxf(acc[2] * dinv + b0.z, 0.f);
    float o3 = fmaxf(acc[3] * dinv + b0.w, 0.f);
    float o4 = fmaxf(acc[4] * dinv + b4.x, 0.f);
    float o5 = fmaxf(acc[5] * dinv + b4.y, 0.f);
    float o6 = fmaxf(acc[6] * dinv + b4.z, 0.f);
    float o7 = fmaxf(acc[7] * dinv + b4.w, 0.f);
    if (half == 0) {
        uint4 Hv;
        Hv.x = (unsigned)f2bf(o0) | ((unsigned)f2bf(o1) << 16);
        Hv.y = (unsigned)f2bf(o2) | ((unsigned)f2bf(o3) << 16);
        Hv.z = (unsigned)f2bf(o4) | ((unsigned)f2bf(o5) << 16);
        Hv.w = (unsigned)f2bf(o6) | ((unsigned)f2bf(o7) << 16);
        *(uint4*)(h1h + (size_t)n * 256 + q * 8) = Hv;
    }
}

// gather layer 2 (1 head, C=64): 1 wave/node, 4 edge-groups of 16 lanes,
// lane q=lane&15 owns 4 cols (8B). Fused uv = (h2+b2) . Wc halves.
// (round-10 measured-good shape; r11's 8-group variant regressed 3x)
__global__ __launch_bounds__(256) void k_gather2(const unsigned short* __restrict__ xp2b,
                                                 const float* __restrict__ as, const float* __restrict__ ad,
                                                 const int* __restrict__ rowptr, const int* __restrict__ csr_src,
                                                 const float* __restrict__ b2, const float* __restrict__ Wc,
                                                 float* __restrict__ uv, int M) {
    int wv = threadIdx.x >> 6, lane = threadIdx.x & 63;
    int n = blockIdx.x * 4 + wv;
    if (n >= M) return;
    int g = lane >> 4, q = lane & 15;
    float adv = ad[n];
    int start = rowptr[n], end = rowptr[n + 1];
    float acc[4] = {0.f, 0.f, 0.f, 0.f};
    float den = 0.f;
    for (int e = start; e < end; e += 4) {
        int ee = e + g;
        bool ok = ee < end;
        int s = csr_src[ok ? ee : start];
        uint2 v = *(const uint2*)(xp2b + (size_t)s * 64 + q * 4);
        float pw = ok ? __expf(lrelu(as[s] + adv)) : 0.f;
        den += pw;
        acc[0] += pw * bflo(v.x); acc[1] += pw * bfhi(v.x);
        acc[2] += pw * bflo(v.y); acc[3] += pw * bfhi(v.y);
    }
#pragma unroll
    for (int j = 0; j < 4; j++) {
        acc[j] += __shfl_xor(acc[j], 16, 64);
        acc[j] += __shfl_xor(acc[j], 32, 64);
    }
    den += __shfl_xor(den, 16, 64);
    den += __shfl_xor(den, 32, 64);
    float dinv = 1.f / (den + 1e-16f);
    float pr[8] = {0.f, 0.f, 0.f, 0.f, 0.f, 0.f, 0.f, 0.f};
#pragma unroll
    for (int j = 0; j < 4; j++) {
        int c = q * 4 + j;
        float val = acc[j] * dinv + b2[c];
#pragma unroll
        for (int k = 0; k < 4; k++) {
            pr[k]     += val * Wc[c * 4 + k];
            pr[4 + k] += val * Wc[(64 + c) * 4 + k];
        }
    }
#pragma unroll
    for (int off = 1; off <= 8; off <<= 1)
#pragma unroll
        for (int j = 0; j < 8; j++) pr[j] += __shfl_xor(pr[j], off, 64);
    if (lane == 0) {
        float4* o = (float4*)(uv + (size_t)n * 8);
        o[0] = make_float4(pr[0], pr[1], pr[2], pr[3]);
        o[1] = make_float4(pr[4], pr[5], pr[6], pr[7]);
    }
}

__global__ __launch_bounds__(256) void k_classify(const int* __restrict__ ei, const float* __restrict__ uv,
                                                  const float* __restrict__ bc, float* __restrict__ out, int E) {
    int e = blockIdx.x * 256 + threadIdx.x;
    if (e >= E) return;
    int r = ei[e];
    int c = ei[E + e];
    float4 u = *(const float4*)(uv + (size_t)r * 8);
    float4 v = *(const float4*)(uv + (size_t)c * 8 + 4);
    float4 o;
    o.x = u.x + v.x + bc[0];
    o.y = u.y + v.y + bc[1];
    o.z = u.z + v.z + bc[2];
    o.w = u.w + v.w + bc[3];
    *(float4*)(out + (size_t)e * 4) = o;
}

// ---------------------------------------------------------------------------

extern "C" void kernel_launch(void* const* d_in, const int* in_sizes, int n_in,
                              void* d_out, int out_size, void* d_ws, size_t ws_size,
                              hipStream_t stream) {
    const float* x    = (const float*)d_in[0];
    const int*   ei   = (const int*)d_in[1];
    // d_in[2] = w (edge weights) ignored by reference
    const float* W1   = (const float*)d_in[3];
    const float* atS1 = (const float*)d_in[4];
    const float* atD1 = (const float*)d_in[5];
    const float* b1   = (const float*)d_in[6];
    const float* W2   = (const float*)d_in[7];
    const float* atS2 = (const float*)d_in[8];
    const float* atD2 = (const float*)d_in[9];
    const float* b2   = (const float*)d_in[10];
    const float* Wc   = (const float*)d_in[11];
    const float* bc   = (const float*)d_in[12];
    float* out = (float*)d_out;

    const int Nn = in_sizes[0] / 256;   // nodes
    const int E = in_sizes[1] / 2;
    const int Etot = E + Nn;
    const int NB = (Nn + 255) / 256;    // scan blocks

    char* w = (char*)d_ws;
    size_t off = 0;
    auto alloc = [&](size_t b) { size_t o = off; off = (o + b + 255) & ~(size_t)255; return o; };
    size_t oXH  = alloc((size_t)Nn * 256 * 2);   // x bf16; later h1h
    size_t oXPB = alloc((size_t)Nn * 256 * 2);   // xp bf16; later xp2b|uv
    size_t oAS1 = alloc((size_t)Nn * 4 * 4);
    size_t oAD1 = alloc((size_t)Nn * 4 * 4);
    size_t oDEG = alloc((size_t)Nn * 4);
    size_t oCUR = alloc((size_t)Nn * 4);
    size_t oRP  = alloc((size_t)(Nn + 1) * 4);
    size_t oCSR = alloc((size_t)Etot * 4);
    size_t oW1H = alloc((size_t)256 * 256 * 2);
    size_t oW1L = alloc((size_t)256 * 256 * 2);
    size_t oW2H = alloc((size_t)256 * 64 * 2);
    size_t oW2L = alloc((size_t)256 * 64 * 2);
    size_t oBS  = alloc((size_t)NB * 4);
    size_t oBO  = alloc((size_t)NB * 4);
    (void)ws_size;

    unsigned short* xh   = (unsigned short*)(w + oXH);
    unsigned short* h1h  = (unsigned short*)(w + oXH);   // alias: xh dead after gemm1
    unsigned short* xpb  = (unsigned short*)(w + oXPB);
    unsigned short* xp2b = (unsigned short*)(w + oXPB);  // alias: xpb dead after gather1
    float* uv  = (float*)(w + oXPB + (size_t)Nn * 64 * 2 + 256);
    uv = (float*)(((uintptr_t)uv + 255) & ~(uintptr_t)255);
    float* as1 = (float*)(w + oAS1);
    float* ad1 = (float*)(w + oAD1);
    float* as2 = (float*)(w + oAS1);                     // alias: as1 dead after gather1
    float* ad2 = (float*)(w + oAD1);
    int* deg    = (int*)(w + oDEG);
    int* cur    = (int*)(w + oCUR);
    int* rowptr = (int*)(w + oRP);
    int* csr    = (int*)(w + oCSR);
    int* bsum   = (int*)(w + oBS);
    int* boff   = (int*)(w + oBO);
    unsigned short* W1hT = (unsigned short*)(w + oW1H);
    unsigned short* W1lT = (unsigned short*)(w + oW1L);
    unsigned short* W2hT = (unsigned short*)(w + oW2H);
    unsigned short* W2lT = (unsigned short*)(w + oW2L);

    // CSR build (parallel scan)
    k_init<<<NB, 256, 0, stream>>>(deg, cur, Nn);
    k_hist<<<(E + 255) / 256, 256, 0, stream>>>(ei, deg, E);
    k_bsum<<<NB, 256, 0, stream>>>(deg, bsum, Nn);
    k_bscan<<<1, 256, 0, stream>>>(bsum, boff, rowptr, NB, Nn);
    k_rowptr<<<NB, 256, 0, stream>>>(deg, boff, rowptr, Nn);
    k_scatter<<<(Etot + 255) / 256, 256, 0, stream>>>(ei, rowptr, cur, csr, E, Nn);

    // packing
    k_pack_hi<<<2048, 256, 0, stream>>>(x, xh, (long)Nn * 64);
    k_pack_w2<<<(256 * 256 + 64 * 256 + 255) / 256, 256, 0, stream>>>(W1, W2, W1hT, W1lT, W2hT, W2lT);

    // Layer 1: 128x128 tile (WGM=2, WGN=2), grid.y = 2; attn fused
    {
        dim3 g((Nn + 127) / 128, 2);
        k_gemm_lds<2, 2><<<g, 256, 0, stream>>>(xh, W1hT, W1lT, xpb, Nn, 256, 256,
                                                atS1, atD1, as1, ad1, 4);
    }
    k_gather1<<<(Nn + 3) / 4, 256, 0, stream>>>(xpb, as1, ad1, rowptr, csr, b1, h1h, Nn);

    // Layer 2: 256x64 tile (WGM=4, WGN=1), grid.y = 1; attn fused
    {
        dim3 g((Nn + 255) / 256, 1);
        k_gemm_lds<4, 1><<<g, 256, 0, stream>>>(h1h, W2hT, W2lT, xp2b, Nn, 64, 256,
                                                atS2, atD2, as2, ad2, 1);
    }
    k_gather2<<<(Nn + 3) / 4, 256, 0, stream>>>(xp2b, as2, ad2, rowptr, csr, b2, Wc, uv, Nn);

    // Edge classifier
    k_classify<<<(E + 255) / 256, 256, 0, stream>>>(ei, uv, bc, out, E);
}

// Round 13
// 271.599 us; speedup vs baseline: 1.2260x; 1.0382x over previous
//
#include <hip/hip_runtime.h>

// ---------------------------------------------------------------------------
// GAT edge classifier, MI355X.
//   memset deg|cur=0 -> k_prep (hist + pack x->bf16 + pack W splits, one
//     block-partitioned dispatch) -> 3-phase parallel scan (deg+1 folded for
//     self-loops) -> scatter                              [int atomics only]
//   GEMM (m97 structure): global_load_lds width=16 staging, BK=64, 2-barrier
//     K-loop, XOR-swizzle both sides. 2-term split (ah*bh + ah*bl = bf16(A)*B).
//     Fused attention epilogue -> as/ad from f32 accs.
//   gather1: 1 wave/node, 16B/lane uint4, half-wave per edge (2 edges/instr),
//     8-edge main loop (4 loads in flight), fused p=exp(lrelu(.)) -> h1 bf16
//   GEMM2 -> xp2b (+attn2 fused)
//   gather2: r10 shape (16-lane groups, uint2) + 2-edge unroll (dual acc/den
//     chains, 2 loads in flight; r11 lesson: do NOT change group geometry)
//   classify: out[e] = u[row] + v[col] + bc
// ---------------------------------------------------------------------------

#define NEG 0.2f

typedef __attribute__((ext_vector_type(8))) short bf16x8;
typedef __attribute__((ext_vector_type(4))) float f32x4;

__device__ __forceinline__ unsigned short f2bf(float f) {
    unsigned int u = __float_as_uint(f);
    unsigned int r = (u + 0x7FFFu + ((u >> 16) & 1u)) >> 16;   // RNE
    return (unsigned short)r;
}
__device__ __forceinline__ float bf2f(unsigned short h) {
    return __uint_as_float(((unsigned int)h) << 16);
}
__device__ __forceinline__ float bflo(unsigned int u) { return __uint_as_float(u << 16); }
__device__ __forceinline__ float bfhi(unsigned int u) { return __uint_as_float(u & 0xFFFF0000u); }
__device__ __forceinline__ float lrelu(float x) { return x > 0.f ? x : NEG * x; }

// async global->LDS, 16 bytes per lane. Dest is wave-uniform base + lane*16.
__device__ __forceinline__ void async16(const void* g, void* l) {
    __builtin_amdgcn_global_load_lds(
        (const __attribute__((address_space(1))) unsigned int*)g,
        (__attribute__((address_space(3))) unsigned int*)l, 16, 0, 0);
}

// ------------------------- prep: hist + packs (merged) ---------------------
// blocks [0,1024): edge histogram (deg starts 0; self-loop +1 folded later)
// blocks [1024,2048): x -> bf16 pack (grid-stride over n4 float4s)
// blocks [2048,2368): W1/W2 -> transposed hi/lo bf16 splits
__global__ __launch_bounds__(256) void k_prep(const int* __restrict__ ei, int* __restrict__ deg, int E,
                                              const float* __restrict__ x, unsigned short* __restrict__ xh,
                                              long n4,
                                              const float* __restrict__ W1, const float* __restrict__ W2,
                                              unsigned short* __restrict__ W1hT, unsigned short* __restrict__ W1lT,
                                              unsigned short* __restrict__ W2hT, unsigned short* __restrict__ W2lT) {
    int b = blockIdx.x;
    if (b < 1024) {
        for (long e = (long)b * 256 + threadIdx.x; e < E; e += (long)1024 * 256)
            atomicAdd(&deg[ei[E + e]], 1);   // dst = ei[1][e]
    } else if (b < 2048) {
        for (long i = (long)(b - 1024) * 256 + threadIdx.x; i < n4; i += (long)1024 * 256) {
            float4 v = ((const float4*)x)[i];
            ((ushort4*)xh)[i] = make_ushort4(f2bf(v.x), f2bf(v.y), f2bf(v.z), f2bf(v.w));
        }
    } else {
        int t = (b - 2048) * 256 + threadIdx.x;
        if (t < 256 * 256) {
            int n = t >> 8, k = t & 255;        // W1T [N=256,K=256]
            float v = W1[k * 256 + n];
            unsigned short h = f2bf(v);
            W1hT[t] = h;
            W1lT[t] = f2bf(v - bf2f(h));
        } else {
            int t2 = t - 256 * 256;             // W2T [N=64,K=256]
            int n = t2 >> 8, k = t2 & 255;
            float v = W2[k * 64 + n];
            unsigned short h = f2bf(v);
            W2hT[t2] = h;
            W2lT[t2] = f2bf(v - bf2f(h));
        }
    }
}

// ------------------------------- CSR scan ---------------------------------
// deg[] counts real edges only; +1 per node (self-loop) folded in here.

__global__ __launch_bounds__(256) void k_bsum(const int* __restrict__ deg, int* __restrict__ bsum, int n) {
    int i = blockIdx.x * 256 + threadIdx.x;
    int v = (i < n) ? deg[i] + 1 : 0;
#pragma unroll
    for (int off = 1; off < 64; off <<= 1) v += __shfl_xor(v, off, 64);
    __shared__ int ws[4];
    int wv = threadIdx.x >> 6, l = threadIdx.x & 63;
    if (l == 0) ws[wv] = v;
    __syncthreads();
    if (threadIdx.x == 0) bsum[blockIdx.x] = ws[0] + ws[1] + ws[2] + ws[3];
}

// exclusive scan of bsum[0..nb), nb <= 256; also writes rowptr[n] = total
__global__ __launch_bounds__(256) void k_bscan(const int* __restrict__ bsum, int* __restrict__ boff,
                                               int* __restrict__ rowptr, int nb, int n) {
    __shared__ int s[256];
    int t = threadIdx.x;
    int v = (t < nb) ? bsum[t] : 0;
    s[t] = v;
    __syncthreads();
    for (int off = 1; off < 256; off <<= 1) {
        int u = (t >= off) ? s[t - off] : 0;
        __syncthreads();
        s[t] += u;
        __syncthreads();
    }
    if (t < nb) boff[t] = s[t] - v;
    if (t == nb - 1) rowptr[n] = s[t];
}

__global__ __launch_bounds__(256) void k_rowptr(const int* __restrict__ deg, const int* __restrict__ boff,
                                                int* __restrict__ rowptr, int n) {
    __shared__ int s[256];
    int i = blockIdx.x * 256 + threadIdx.x;
    int t = threadIdx.x;
    int v = (i < n) ? deg[i] + 1 : 0;
    s[t] = v;
    __syncthreads();
    for (int off = 1; off < 256; off <<= 1) {
        int u = (t >= off) ? s[t - off] : 0;
        __syncthreads();
        s[t] += u;
        __syncthreads();
    }
    if (i < n) rowptr[i] = boff[blockIdx.x] + s[t] - v;
}

__global__ __launch_bounds__(256) void k_scatter(const int* __restrict__ ei, const int* __restrict__ rowptr,
                                                 int* cur, int* csr_src, int E, int N) {
    int e = blockIdx.x * 256 + threadIdx.x;
    if (e < E) {
        int d = ei[E + e];
        int pos = rowptr[d] + atomicAdd(&cur[d], 1);
        csr_src[pos] = ei[e];
    } else if (e < E + N) {
        int i = e - E;  // self loop
        int pos = rowptr[i] + atomicAdd(&cur[i], 1);
        csr_src[pos] = i;
    }
}

// ------------------------------- MFMA GEMM (LDS, m97 structure) -----------
// C[M,N] = bf16(A)[M,K] @ B[K,N] (B as hi/lo bf16 [N,K], 2-term).
// Fused attn epilogue: wave owns one head's 64 cols -> as/ad row dots.
template<int WGM, int WGN>
__global__ __launch_bounds__(256, 2) void k_gemm_lds(const unsigned short* __restrict__ Ah,
                                                     const unsigned short* __restrict__ BhT,
                                                     const unsigned short* __restrict__ BlT,
                                                     unsigned short* __restrict__ Cb, int M, int N, int K,
                                                     const float* __restrict__ att_s,
                                                     const float* __restrict__ att_d,
                                                     float* __restrict__ as, float* __restrict__ ad, int H) {
    constexpr int BM = WGM * 64, BN = WGN * 64;
    __shared__ char lds[BM * 128 + BN * 256];      // Ah | Bh | Bl, rows*128B
    char* LAh = lds;
    char* LBh = lds + BM * 128;
    char* LBl = lds + BM * 128 + BN * 128;

    const int t = threadIdx.x, wv = t >> 6, l = t & 63;
    const int r = l & 15, hk = l >> 4;
    const int m0 = blockIdx.x * BM;
    const int n0 = blockIdx.y * BN;
    const int wr = wv / WGN, wc = wv % WGN;
    const int wrow0 = wr * 64, wcol0 = wc * 64;

    f32x4 acc[4][4];
#pragma unroll
    for (int i = 0; i < 4; i++)
#pragma unroll
        for (int j = 0; j < 4; j++) acc[i][j] = f32x4{0, 0, 0, 0};

    const int lrow8 = l >> 3;                       // 0..7
    const int cbs = ((l & 7) ^ lrow8) << 4;         // inverse-swizzled src col byte
    const size_t K2 = (size_t)K * 2;
    const int NCH = K >> 6;

    for (int c = 0; c < NCH; ++c) {
        const int kk2 = c * 128;
        {
            const int SA = BM / 8;
            for (int i = wv; i < SA; i += 4) {
                int row = i * 8 + lrow8;
                size_t go = (size_t)(m0 + row) * K2 + kk2 + cbs;
                async16((const char*)Ah + go, LAh + i * 1024);
            }
            const int SB = BN / 8;
            for (int i = wv; i < SB; i += 4) {
                int row = i * 8 + lrow8;
                size_t go = (size_t)(n0 + row) * K2 + kk2 + cbs;
                async16((const char*)BhT + go, LBh + i * 1024);
                async16((const char*)BlT + go, LBl + i * 1024);
            }
        }
        __syncthreads();
#pragma unroll
        for (int ks = 0; ks < 2; ++ks) {
            const int cb = ks * 64 + hk * 16;
            bf16x8 a_h[4], b_h[4], b_l[4];
#pragma unroll
            for (int fm = 0; fm < 4; ++fm) {
                int row = wrow0 + fm * 16 + r;
                int ad_ = row * 128 + (cb ^ ((row & 7) << 4));
                a_h[fm] = *(const bf16x8*)(LAh + ad_);
            }
#pragma unroll
            for (int fn = 0; fn < 4; ++fn) {
                int row = wcol0 + fn * 16 + r;
                int ad_ = row * 128 + (cb ^ ((row & 7) << 4));
                b_h[fn] = *(const bf16x8*)(LBh + ad_);
                b_l[fn] = *(const bf16x8*)(LBl + ad_);
            }
#pragma unroll
            for (int fm = 0; fm < 4; ++fm)
#pragma unroll
                for (int fn = 0; fn < 4; ++fn) {
                    acc[fm][fn] = __builtin_amdgcn_mfma_f32_16x16x32_bf16(a_h[fm], b_h[fn], acc[fm][fn], 0, 0, 0);
                    acc[fm][fn] = __builtin_amdgcn_mfma_f32_16x16x32_bf16(a_h[fm], b_l[fn], acc[fm][fn], 0, 0, 0);
                }
        }
        if (c + 1 < NCH) __syncthreads();
    }

    // ---- C write (C/D frag: col=lane&15, row=(lane>>4)*4+j) ----
#pragma unroll
    for (int fm = 0; fm < 4; ++fm)
#pragma unroll
        for (int fn = 0; fn < 4; ++fn)
#pragma unroll
            for (int j = 0; j < 4; ++j) {
                int m = m0 + wrow0 + fm * 16 + hk * 4 + j;
                if (m < M) Cb[(size_t)m * N + n0 + wcol0 + fn * 16 + r] = f2bf(acc[fm][fn][j]);
            }

    // ---- fused attention dots for this wave's head (from f32 accs) ----
    {
        int head = (n0 + wcol0) >> 6;
        float satt[4], datt[4];
#pragma unroll
        for (int fn = 0; fn < 4; ++fn) {
            satt[fn] = att_s[head * 64 + fn * 16 + r];
            datt[fn] = att_d[head * 64 + fn * 16 + r];
        }
#pragma unroll
        for (int fm = 0; fm < 4; ++fm)
#pragma unroll
            for (int j = 0; j < 4; ++j) {
                float ps = 0.f, pd = 0.f;
#pragma unroll
                for (int fn = 0; fn < 4; ++fn) {
                    ps += satt[fn] * acc[fm][fn][j];
                    pd += datt[fn] * acc[fm][fn][j];
                }
#pragma unroll
                for (int off = 1; off <= 8; off <<= 1) {
                    ps += __shfl_xor(ps, off, 64);
                    pd += __shfl_xor(pd, off, 64);
                }
                if (r == 0) {
                    int m = m0 + wrow0 + fm * 16 + hk * 4 + j;
                    if (m < M) { as[m * H + head] = ps; ad[m * H + head] = pd; }
                }
            }
    }
}

// ------------------------------- gathers ----------------------------------

// gather layer 1: 1 wave/node. Lane layout: half=lane>>5 picks the edge of a
// pair, q=lane&31 owns cols q*8..q*8+7 (uint4 = 16B), head h=q>>3.
// One VMEM instr covers 2 edges; 8-edge main loop = 4 loads in flight.
__global__ __launch_bounds__(256) void k_gather1(const unsigned short* __restrict__ xpb,
                                                 const float* __restrict__ as, const float* __restrict__ ad,
                                                 const int* __restrict__ rowptr, const int* __restrict__ csr_src,
                                                 const float* __restrict__ b1,
                                                 unsigned short* __restrict__ h1h, int M) {
    int wv = threadIdx.x >> 6, lane = threadIdx.x & 63;
    int n = blockIdx.x * 4 + wv;
    if (n >= M) return;
    int half = lane >> 5;
    int q = lane & 31;
    int h = q >> 3;
    float adv = ad[n * 4 + h];
    int start = rowptr[n], end = rowptr[n + 1];
    float acc[8] = {0.f, 0.f, 0.f, 0.f, 0.f, 0.f, 0.f, 0.f};
    float den = 0.f;

    auto edge = [&](int s, uint4 v) {
        float p = __expf(lrelu(as[s * 4 + h] + adv));
        den += p;
        acc[0] += p * bflo(v.x); acc[1] += p * bfhi(v.x);
        acc[2] += p * bflo(v.y); acc[3] += p * bfhi(v.y);
        acc[4] += p * bflo(v.z); acc[5] += p * bfhi(v.z);
        acc[6] += p * bflo(v.w); acc[7] += p * bfhi(v.w);
    };

    int e = start;
    for (; e + 7 < end; e += 8) {
        int sa = csr_src[e + half];
        int sb = csr_src[e + 2 + half];
        int sc = csr_src[e + 4 + half];
        int sd = csr_src[e + 6 + half];
        uint4 va = *(const uint4*)(xpb + (size_t)sa * 256 + q * 8);
        uint4 vb = *(const uint4*)(xpb + (size_t)sb * 256 + q * 8);
        uint4 vc = *(const uint4*)(xpb + (size_t)sc * 256 + q * 8);
        uint4 vd = *(const uint4*)(xpb + (size_t)sd * 256 + q * 8);
        edge(sa, va); edge(sb, vb); edge(sc, vc); edge(sd, vd);
    }
    if (e + 3 < end) {
        int sa = csr_src[e + half];
        int sb = csr_src[e + 2 + half];
        uint4 va = *(const uint4*)(xpb + (size_t)sa * 256 + q * 8);
        uint4 vb = *(const uint4*)(xpb + (size_t)sb * 256 + q * 8);
        edge(sa, va); edge(sb, vb);
        e += 4;
    }
    if (e + 1 < end) {
        int sa = csr_src[e + half];
        uint4 va = *(const uint4*)(xpb + (size_t)sa * 256 + q * 8);
        edge(sa, va);
        e += 2;
    }
    if (e < end && half == 0) {
        int sa = csr_src[e];
        uint4 va = *(const uint4*)(xpb + (size_t)sa * 256 + q * 8);
        edge(sa, va);
    }

    // combine the two halves
#pragma unroll
    for (int j = 0; j < 8; j++) acc[j] += __shfl_xor(acc[j], 32, 64);
    den += __shfl_xor(den, 32, 64);

    float dinv = 1.f / (den + 1e-16f);
    float4 b0 = *(const float4*)(b1 + q * 8);
    float4 b4 = *(const float4*)(b1 + q * 8 + 4);
    float o0 = fmaxf(acc[0] * dinv + b0.x, 0.f);
    float o1 = fmaxf(acc[1] * dinv + b0.y, 0.f);
    float o2 = fmaxf(acc[2] * dinv + b0.z, 0.f);
    float o3 = fmaxf(acc[3] * dinv + b0.w, 0.f);
    float o4 = fmaxf(acc[4] * dinv + b4.x, 0.f);
    float o5 = fmaxf(acc[5] * dinv + b4.y, 0.f);
    float o6 = fmaxf(acc[6] * dinv + b4.z, 0.f);
    float o7 = fmaxf(acc[7] * dinv + b4.w, 0.f);
    if (half == 0) {
        uint4 Hv;
        Hv.x = (unsigned)f2bf(o0) | ((unsigned)f2bf(o1) << 16);
        Hv.y = (unsigned)f2bf(o2) | ((unsigned)f2bf(o3) << 16);
        Hv.z = (unsigned)f2bf(o4) | ((unsigned)f2bf(o5) << 16);
        Hv.w = (unsigned)f2bf(o6) | ((unsigned)f2bf(o7) << 16);
        *(uint4*)(h1h + (size_t)n * 256 + q * 8) = Hv;
    }
}

// gather layer 2 (1 head, C=64): 1 wave/node, 4 edge-groups of 16 lanes,
// lane q=lane&15 owns 4 cols (8B). r10 shape + 2-edge unroll (dual acc/den).
// Fused uv = (h2+b2) . Wc halves.
__global__ __launch_bounds__(256) void k_gather2(const unsigned short* __restrict__ xp2b,
                                                 const float* __restrict__ as, const float* __restrict__ ad,
                                                 const int* __restrict__ rowptr, const int* __restrict__ csr_src,
                                                 const float* __restrict__ b2, const float* __restrict__ Wc,
                                                 float* __restrict__ uv, int M) {
    int wv = threadIdx.x >> 6, lane = threadIdx.x & 63;
    int n = blockIdx.x * 4 + wv;
    if (n >= M) return;
    int g = lane >> 4, q = lane & 15;
    float adv = ad[n];
    int start = rowptr[n], end = rowptr[n + 1];
    float acc0[4] = {0.f, 0.f, 0.f, 0.f}, acc1[4] = {0.f, 0.f, 0.f, 0.f};
    float den0 = 0.f, den1 = 0.f;
    int e = start;
    // main loop: 8 edges/iter, each group handles e+g and e+4+g (2 loads in flight)
    for (; e + 7 < end; e += 8) {
        int s0 = csr_src[e + g];
        int s1 = csr_src[e + 4 + g];
        uint2 v0 = *(const uint2*)(xp2b + (size_t)s0 * 64 + q * 4);
        uint2 v1 = *(const uint2*)(xp2b + (size_t)s1 * 64 + q * 4);
        float p0 = __expf(lrelu(as[s0] + adv));
        float p1 = __expf(lrelu(as[s1] + adv));
        den0 += p0; den1 += p1;
        acc0[0] += p0 * bflo(v0.x); acc0[1] += p0 * bfhi(v0.x);
        acc0[2] += p0 * bflo(v0.y); acc0[3] += p0 * bfhi(v0.y);
        acc1[0] += p1 * bflo(v1.x); acc1[1] += p1 * bfhi(v1.x);
        acc1[2] += p1 * bflo(v1.y); acc1[3] += p1 * bfhi(v1.y);
    }
    // tail: 4-edge predicated steps (r10 form)
    for (; e < end; e += 4) {
        int ee = e + g;
        bool ok = ee < end;
        int s = csr_src[ok ? ee : start];
        uint2 v = *(const uint2*)(xp2b + (size_t)s * 64 + q * 4);
        float pw = ok ? __expf(lrelu(as[s] + adv)) : 0.f;
        den0 += pw;
        acc0[0] += pw * bflo(v.x); acc0[1] += pw * bfhi(v.x);
        acc0[2] += pw * bflo(v.y); acc0[3] += pw * bfhi(v.y);
    }
    float acc[4];
#pragma unroll
    for (int j = 0; j < 4; j++) {
        acc[j] = acc0[j] + acc1[j];
        acc[j] += __shfl_xor(acc[j], 16, 64);
        acc[j] += __shfl_xor(acc[j], 32, 64);
    }
    float den = den0 + den1;
    den += __shfl_xor(den, 16, 64);
    den += __shfl_xor(den, 32, 64);
    float dinv = 1.f / (den + 1e-16f);
    float pr[8] = {0.f, 0.f, 0.f, 0.f, 0.f, 0.f, 0.f, 0.f};
#pragma unroll
    for (int j = 0; j < 4; j++) {
        int c = q * 4 + j;
        float val = acc[j] * dinv + b2[c];
#pragma unroll
        for (int k = 0; k < 4; k++) {
            pr[k]     += val * Wc[c * 4 + k];
            pr[4 + k] += val * Wc[(64 + c) * 4 + k];
        }
    }
#pragma unroll
    for (int off = 1; off <= 8; off <<= 1)
#pragma unroll
        for (int j = 0; j < 8; j++) pr[j] += __shfl_xor(pr[j], off, 64);
    if (lane == 0) {
        float4* o = (float4*)(uv + (size_t)n * 8);
        o[0] = make_float4(pr[0], pr[1], pr[2], pr[3]);
        o[1] = make_float4(pr[4], pr[5], pr[6], pr[7]);
    }
}

__global__ __launch_bounds__(256) void k_classify(const int* __restrict__ ei, const float* __restrict__ uv,
                                                  const float* __restrict__ bc, float* __restrict__ out, int E) {
    int e = blockIdx.x * 256 + threadIdx.x;
    if (e >= E) return;
    int r = ei[e];
    int c = ei[E + e];
    float4 u = *(const float4*)(uv + (size_t)r * 8);
    float4 v = *(const float4*)(uv + (size_t)c * 8 + 4);
    float4 o;
    o.x = u.x + v.x + bc[0];
    o.y = u.y + v.y + bc[1];
    o.z = u.z + v.z + bc[2];
    o.w = u.w + v.w + bc[3];
    *(float4*)(out + (size_t)e * 4) = o;
}

// ---------------------------------------------------------------------------

extern "C" void kernel_launch(void* const* d_in, const int* in_sizes, int n_in,
                              void* d_out, int out_size, void* d_ws, size_t ws_size,
                              hipStream_t stream) {
    const float* x    = (const float*)d_in[0];
    const int*   ei   = (const int*)d_in[1];
    // d_in[2] = w (edge weights) ignored by reference
    const float* W1   = (const float*)d_in[3];
    const float* atS1 = (const float*)d_in[4];
    const float* atD1 = (const float*)d_in[5];
    const float* b1   = (const float*)d_in[6];
    const float* W2   = (const float*)d_in[7];
    const float* atS2 = (const float*)d_in[8];
    const float* atD2 = (const float*)d_in[9];
    const float* b2   = (const float*)d_in[10];
    const float* Wc   = (const float*)d_in[11];
    const float* bc   = (const float*)d_in[12];
    float* out = (float*)d_out;

    const int Nn = in_sizes[0] / 256;   // nodes
    const int E = in_sizes[1] / 2;
    const int Etot = E + Nn;
    const int NB = (Nn + 255) / 256;    // scan blocks

    char* w = (char*)d_ws;
    size_t off = 0;
    auto alloc = [&](size_t b) { size_t o = off; off = (o + b + 255) & ~(size_t)255; return o; };
    size_t oXH  = alloc((size_t)Nn * 256 * 2);   // x bf16; later h1h
    size_t oXPB = alloc((size_t)Nn * 256 * 2);   // xp bf16; later xp2b|uv
    size_t oAS1 = alloc((size_t)Nn * 4 * 4);
    size_t oAD1 = alloc((size_t)Nn * 4 * 4);
    size_t oDEG = alloc((size_t)Nn * 4);
    size_t oCUR = alloc((size_t)Nn * 4);
    size_t oRP  = alloc((size_t)(Nn + 1) * 4);
    size_t oCSR = alloc((size_t)Etot * 4);
    size_t oW1H = alloc((size_t)256 * 256 * 2);
    size_t oW1L = alloc((size_t)256 * 256 * 2);
    size_t oW2H = alloc((size_t)256 * 64 * 2);
    size_t oW2L = alloc((size_t)256 * 64 * 2);
    size_t oBS  = alloc((size_t)NB * 4);
    size_t oBO  = alloc((size_t)NB * 4);
    (void)ws_size;

    unsigned short* xh   = (unsigned short*)(w + oXH);
    unsigned short* h1h  = (unsigned short*)(w + oXH);   // alias: xh dead after gemm1
    unsigned short* xpb  = (unsigned short*)(w + oXPB);
    unsigned short* xp2b = (unsigned short*)(w + oXPB);  // alias: xpb dead after gather1
    float* uv  = (float*)(w + oXPB + (size_t)Nn * 64 * 2 + 256);
    uv = (float*)(((uintptr_t)uv + 255) & ~(uintptr_t)255);
    float* as1 = (float*)(w + oAS1);
    float* ad1 = (float*)(w + oAD1);
    float* as2 = (float*)(w + oAS1);                     // alias: as1 dead after gather1
    float* ad2 = (float*)(w + oAD1);
    int* deg    = (int*)(w + oDEG);
    int* cur    = (int*)(w + oCUR);
    int* rowptr = (int*)(w + oRP);
    int* csr    = (int*)(w + oCSR);
    int* bsum   = (int*)(w + oBS);
    int* boff   = (int*)(w + oBO);
    unsigned short* W1hT = (unsigned short*)(w + oW1H);
    unsigned short* W1lT = (unsigned short*)(w + oW1L);
    unsigned short* W2hT = (unsigned short*)(w + oW2H);
    unsigned short* W2lT = (unsigned short*)(w + oW2L);

    // zero deg + cur (replaces k_init; deg now counts real edges, +1 folded in scan)
    hipMemsetAsync(deg, 0, (size_t)Nn * 4, stream);
    hipMemsetAsync(cur, 0, (size_t)Nn * 4, stream);

    // merged prep: hist + pack x + pack W (independent jobs, one dispatch)
    k_prep<<<2368, 256, 0, stream>>>(ei, deg, E, x, xh, (long)Nn * 64,
                                     W1, W2, W1hT, W1lT, W2hT, W2lT);

    // CSR scan + scatter
    k_bsum<<<NB, 256, 0, stream>>>(deg, bsum, Nn);
    k_bscan<<<1, 256, 0, stream>>>(bsum, boff, rowptr, NB, Nn);
    k_rowptr<<<NB, 256, 0, stream>>>(deg, boff, rowptr, Nn);
    k_scatter<<<(Etot + 255) / 256, 256, 0, stream>>>(ei, rowptr, cur, csr, E, Nn);

    // Layer 1: 128x128 tile (WGM=2, WGN=2), grid.y = 2; attn fused
    {
        dim3 g((Nn + 127) / 128, 2);
        k_gemm_lds<2, 2><<<g, 256, 0, stream>>>(xh, W1hT, W1lT, xpb, Nn, 256, 256,
                                                atS1, atD1, as1, ad1, 4);
    }
    k_gather1<<<(Nn + 3) / 4, 256, 0, stream>>>(xpb, as1, ad1, rowptr, csr, b1, h1h, Nn);

    // Layer 2: 256x64 tile (WGM=4, WGN=1), grid.y = 1; attn fused
    {
        dim3 g((Nn + 255) / 256, 1);
        k_gemm_lds<4, 1><<<g, 256, 0, stream>>>(h1h, W2hT, W2lT, xp2b, Nn, 64, 256,
                                                atS2, atD2, as2, ad2, 1);
    }
    k_gather2<<<(Nn + 3) / 4, 256, 0, stream>>>(xp2b, as2, ad2, rowptr, csr, b2, Wc, uv, Nn);

    // Edge classifier
    k_classify<<<(E + 255) / 256, 256, 0, stream>>>(ei, uv, bc, out, E);
}

// Round 14
// 262.198 us; speedup vs baseline: 1.2699x; 1.0359x over previous
//
#include <hip/hip_runtime.h>

// ---------------------------------------------------------------------------
// GAT edge classifier, MI355X.
//   memset deg|cur=0 (single, adjacent) -> k_prep (hist + pack x->bf16 +
//     pack W splits, one block-partitioned dispatch) -> bsum -> rowptr
//     (inline bscan: each block redundantly scans the 196 block-sums in LDS,
//     r14: removes the single-block bscan dispatch) -> scatter
//   GEMM (m97 structure): global_load_lds width=16 staging, BK=64, 2-barrier
//     K-loop, XOR-swizzle both sides. 2-term split (ah*bh + ah*bl = bf16(A)*B).
//     Fused attention epilogue -> as/ad from f32 accs.
//   gather1: 1 wave/node, 16B/lane uint4, half-wave per edge (2 edges/instr),
//     8-edge main loop (4 loads in flight), fused p=exp(lrelu(.)) -> h1 bf16
//     [measured at the L3 random-gather floor: 208MB @ 3.7TB/s, 64us]
//   GEMM2 -> xp2b (+attn2 fused)
//   gather2: r10 geometry (16-lane groups, uint2; r11: geometry changes
//     regress) + 4-deep ILP (r14: 16 edges/iter, 4 loads in flight)
//   classify: out[e] = u[row] + v[col] + bc
// ---------------------------------------------------------------------------

#define NEG 0.2f

typedef __attribute__((ext_vector_type(8))) short bf16x8;
typedef __attribute__((ext_vector_type(4))) float f32x4;

__device__ __forceinline__ unsigned short f2bf(float f) {
    unsigned int u = __float_as_uint(f);
    unsigned int r = (u + 0x7FFFu + ((u >> 16) & 1u)) >> 16;   // RNE
    return (unsigned short)r;
}
__device__ __forceinline__ float bf2f(unsigned short h) {
    return __uint_as_float(((unsigned int)h) << 16);
}
__device__ __forceinline__ float bflo(unsigned int u) { return __uint_as_float(u << 16); }
__device__ __forceinline__ float bfhi(unsigned int u) { return __uint_as_float(u & 0xFFFF0000u); }
__device__ __forceinline__ float lrelu(float x) { return x > 0.f ? x : NEG * x; }

// async global->LDS, 16 bytes per lane. Dest is wave-uniform base + lane*16.
__device__ __forceinline__ void async16(const void* g, void* l) {
    __builtin_amdgcn_global_load_lds(
        (const __attribute__((address_space(1))) unsigned int*)g,
        (__attribute__((address_space(3))) unsigned int*)l, 16, 0, 0);
}

// ------------------------- prep: hist + packs (merged) ---------------------
// blocks [0,1024): edge histogram (deg starts 0; self-loop +1 folded in scan)
// blocks [1024,2048): x -> bf16 pack (grid-stride over n4 float4s)
// blocks [2048,2368): W1/W2 -> transposed hi/lo bf16 splits
__global__ __launch_bounds__(256) void k_prep(const int* __restrict__ ei, int* __restrict__ deg, int E,
                                              const float* __restrict__ x, unsigned short* __restrict__ xh,
                                              long n4,
                                              const float* __restrict__ W1, const float* __restrict__ W2,
                                              unsigned short* __restrict__ W1hT, unsigned short* __restrict__ W1lT,
                                              unsigned short* __restrict__ W2hT, unsigned short* __restrict__ W2lT) {
    int b = blockIdx.x;
    if (b < 1024) {
        for (long e = (long)b * 256 + threadIdx.x; e < E; e += (long)1024 * 256)
            atomicAdd(&deg[ei[E + e]], 1);   // dst = ei[1][e]
    } else if (b < 2048) {
        for (long i = (long)(b - 1024) * 256 + threadIdx.x; i < n4; i += (long)1024 * 256) {
            float4 v = ((const float4*)x)[i];
            ((ushort4*)xh)[i] = make_ushort4(f2bf(v.x), f2bf(v.y), f2bf(v.z), f2bf(v.w));
        }
    } else {
        int t = (b - 2048) * 256 + threadIdx.x;
        if (t < 256 * 256) {
            int n = t >> 8, k = t & 255;        // W1T [N=256,K=256]
            float v = W1[k * 256 + n];
            unsigned short h = f2bf(v);
            W1hT[t] = h;
            W1lT[t] = f2bf(v - bf2f(h));
        } else {
            int t2 = t - 256 * 256;             // W2T [N=64,K=256]
            int n = t2 >> 8, k = t2 & 255;
            float v = W2[k * 64 + n];
            unsigned short h = f2bf(v);
            W2hT[t2] = h;
            W2lT[t2] = f2bf(v - bf2f(h));
        }
    }
}

// ------------------------------- CSR scan ---------------------------------
// deg[] counts real edges only; +1 per node (self-loop) folded in here.

__global__ __launch_bounds__(256) void k_bsum(const int* __restrict__ deg, int* __restrict__ bsum, int n) {
    int i = blockIdx.x * 256 + threadIdx.x;
    int v = (i < n) ? deg[i] + 1 : 0;
#pragma unroll
    for (int off = 1; off < 64; off <<= 1) v += __shfl_xor(v, off, 64);
    __shared__ int ws[4];
    int wv = threadIdx.x >> 6, l = threadIdx.x & 63;
    if (l == 0) ws[wv] = v;
    __syncthreads();
    if (threadIdx.x == 0) bsum[blockIdx.x] = ws[0] + ws[1] + ws[2] + ws[3];
}

// rowptr with inline block-sum scan (nb <= 256): every block scans bsum[] in
// LDS and takes its own exclusive prefix; block 0 also writes rowptr[n].
__global__ __launch_bounds__(256) void k_rowptr(const int* __restrict__ deg, const int* __restrict__ bsum,
                                                int* __restrict__ rowptr, int nb, int n) {
    __shared__ int sb[256];
    __shared__ int s[256];
    int t = threadIdx.x;
    int vb = (t < nb) ? bsum[t] : 0;
    sb[t] = vb;
    __syncthreads();
    for (int off = 1; off < 256; off <<= 1) {
        int u = (t >= off) ? sb[t - off] : 0;
        __syncthreads();
        sb[t] += u;
        __syncthreads();
    }
    int boffb = (blockIdx.x == 0) ? 0 : sb[blockIdx.x - 1];
    int i = blockIdx.x * 256 + t;
    int v = (i < n) ? deg[i] + 1 : 0;
    s[t] = v;
    __syncthreads();
    for (int off = 1; off < 256; off <<= 1) {
        int u = (t >= off) ? s[t - off] : 0;
        __syncthreads();
        s[t] += u;
        __syncthreads();
    }
    if (i < n) rowptr[i] = boffb + s[t] - v;
    if (blockIdx.x == 0 && t == 0) rowptr[n] = sb[nb - 1];
}

__global__ __launch_bounds__(256) void k_scatter(const int* __restrict__ ei, const int* __restrict__ rowptr,
                                                 int* cur, int* csr_src, int E, int N) {
    int e = blockIdx.x * 256 + threadIdx.x;
    if (e < E) {
        int d = ei[E + e];
        int pos = rowptr[d] + atomicAdd(&cur[d], 1);
        csr_src[pos] = ei[e];
    } else if (e < E + N) {
        int i = e - E;  // self loop
        int pos = rowptr[i] + atomicAdd(&cur[i], 1);
        csr_src[pos] = i;
    }
}

// ------------------------------- MFMA GEMM (LDS, m97 structure) -----------
// C[M,N] = bf16(A)[M,K] @ B[K,N] (B as hi/lo bf16 [N,K], 2-term).
// Fused attn epilogue: wave owns one head's 64 cols -> as/ad row dots.
template<int WGM, int WGN>
__global__ __launch_bounds__(256, 2) void k_gemm_lds(const unsigned short* __restrict__ Ah,
                                                     const unsigned short* __restrict__ BhT,
                                                     const unsigned short* __restrict__ BlT,
                                                     unsigned short* __restrict__ Cb, int M, int N, int K,
                                                     const float* __restrict__ att_s,
                                                     const float* __restrict__ att_d,
                                                     float* __restrict__ as, float* __restrict__ ad, int H) {
    constexpr int BM = WGM * 64, BN = WGN * 64;
    __shared__ char lds[BM * 128 + BN * 256];      // Ah | Bh | Bl, rows*128B
    char* LAh = lds;
    char* LBh = lds + BM * 128;
    char* LBl = lds + BM * 128 + BN * 128;

    const int t = threadIdx.x, wv = t >> 6, l = t & 63;
    const int r = l & 15, hk = l >> 4;
    const int m0 = blockIdx.x * BM;
    const int n0 = blockIdx.y * BN;
    const int wr = wv / WGN, wc = wv % WGN;
    const int wrow0 = wr * 64, wcol0 = wc * 64;

    f32x4 acc[4][4];
#pragma unroll
    for (int i = 0; i < 4; i++)
#pragma unroll
        for (int j = 0; j < 4; j++) acc[i][j] = f32x4{0, 0, 0, 0};

    const int lrow8 = l >> 3;                       // 0..7
    const int cbs = ((l & 7) ^ lrow8) << 4;         // inverse-swizzled src col byte
    const size_t K2 = (size_t)K * 2;
    const int NCH = K >> 6;

    for (int c = 0; c < NCH; ++c) {
        const int kk2 = c * 128;
        {
            const int SA = BM / 8;
            for (int i = wv; i < SA; i += 4) {
                int row = i * 8 + lrow8;
                size_t go = (size_t)(m0 + row) * K2 + kk2 + cbs;
                async16((const char*)Ah + go, LAh + i * 1024);
            }
            const int SB = BN / 8;
            for (int i = wv; i < SB; i += 4) {
                int row = i * 8 + lrow8;
                size_t go = (size_t)(n0 + row) * K2 + kk2 + cbs;
                async16((const char*)BhT + go, LBh + i * 1024);
                async16((const char*)BlT + go, LBl + i * 1024);
            }
        }
        __syncthreads();
#pragma unroll
        for (int ks = 0; ks < 2; ++ks) {
            const int cb = ks * 64 + hk * 16;
            bf16x8 a_h[4], b_h[4], b_l[4];
#pragma unroll
            for (int fm = 0; fm < 4; ++fm) {
                int row = wrow0 + fm * 16 + r;
                int ad_ = row * 128 + (cb ^ ((row & 7) << 4));
                a_h[fm] = *(const bf16x8*)(LAh + ad_);
            }
#pragma unroll
            for (int fn = 0; fn < 4; ++fn) {
                int row = wcol0 + fn * 16 + r;
                int ad_ = row * 128 + (cb ^ ((row & 7) << 4));
                b_h[fn] = *(const bf16x8*)(LBh + ad_);
                b_l[fn] = *(const bf16x8*)(LBl + ad_);
            }
#pragma unroll
            for (int fm = 0; fm < 4; ++fm)
#pragma unroll
                for (int fn = 0; fn < 4; ++fn) {
                    acc[fm][fn] = __builtin_amdgcn_mfma_f32_16x16x32_bf16(a_h[fm], b_h[fn], acc[fm][fn], 0, 0, 0);
                    acc[fm][fn] = __builtin_amdgcn_mfma_f32_16x16x32_bf16(a_h[fm], b_l[fn], acc[fm][fn], 0, 0, 0);
                }
        }
        if (c + 1 < NCH) __syncthreads();
    }

    // ---- C write (C/D frag: col=lane&15, row=(lane>>4)*4+j) ----
#pragma unroll
    for (int fm = 0; fm < 4; ++fm)
#pragma unroll
        for (int fn = 0; fn < 4; ++fn)
#pragma unroll
            for (int j = 0; j < 4; ++j) {
                int m = m0 + wrow0 + fm * 16 + hk * 4 + j;
                if (m < M) Cb[(size_t)m * N + n0 + wcol0 + fn * 16 + r] = f2bf(acc[fm][fn][j]);
            }

    // ---- fused attention dots for this wave's head (from f32 accs) ----
    {
        int head = (n0 + wcol0) >> 6;
        float satt[4], datt[4];
#pragma unroll
        for (int fn = 0; fn < 4; ++fn) {
            satt[fn] = att_s[head * 64 + fn * 16 + r];
            datt[fn] = att_d[head * 64 + fn * 16 + r];
        }
#pragma unroll
        for (int fm = 0; fm < 4; ++fm)
#pragma unroll
            for (int j = 0; j < 4; ++j) {
                float ps = 0.f, pd = 0.f;
#pragma unroll
                for (int fn = 0; fn < 4; ++fn) {
                    ps += satt[fn] * acc[fm][fn][j];
                    pd += datt[fn] * acc[fm][fn][j];
                }
#pragma unroll
                for (int off = 1; off <= 8; off <<= 1) {
                    ps += __shfl_xor(ps, off, 64);
                    pd += __shfl_xor(pd, off, 64);
                }
                if (r == 0) {
                    int m = m0 + wrow0 + fm * 16 + hk * 4 + j;
                    if (m < M) { as[m * H + head] = ps; ad[m * H + head] = pd; }
                }
            }
    }
}

// ------------------------------- gathers ----------------------------------

// gather layer 1: 1 wave/node. Lane layout: half=lane>>5 picks the edge of a
// pair, q=lane&31 owns cols q*8..q*8+7 (uint4 = 16B), head h=q>>3.
// One VMEM instr covers 2 edges; 8-edge main loop = 4 loads in flight.
__global__ __launch_bounds__(256) void k_gather1(const unsigned short* __restrict__ xpb,
                                                 const float* __restrict__ as, const float* __restrict__ ad,
                                                 const int* __restrict__ rowptr, const int* __restrict__ csr_src,
                                                 const float* __restrict__ b1,
                                                 unsigned short* __restrict__ h1h, int M) {
    int wv = threadIdx.x >> 6, lane = threadIdx.x & 63;
    int n = blockIdx.x * 4 + wv;
    if (n >= M) return;
    int half = lane >> 5;
    int q = lane & 31;
    int h = q >> 3;
    float adv = ad[n * 4 + h];
    int start = rowptr[n], end = rowptr[n + 1];
    float acc[8] = {0.f, 0.f, 0.f, 0.f, 0.f, 0.f, 0.f, 0.f};
    float den = 0.f;

    auto edge = [&](int s, uint4 v) {
        float p = __expf(lrelu(as[s * 4 + h] + adv));
        den += p;
        acc[0] += p * bflo(v.x); acc[1] += p * bfhi(v.x);
        acc[2] += p * bflo(v.y); acc[3] += p * bfhi(v.y);
        acc[4] += p * bflo(v.z); acc[5] += p * bfhi(v.z);
        acc[6] += p * bflo(v.w); acc[7] += p * bfhi(v.w);
    };

    int e = start;
    for (; e + 7 < end; e += 8) {
        int sa = csr_src[e + half];
        int sb = csr_src[e + 2 + half];
        int sc = csr_src[e + 4 + half];
        int sd = csr_src[e + 6 + half];
        uint4 va = *(const uint4*)(xpb + (size_t)sa * 256 + q * 8);
        uint4 vb = *(const uint4*)(xpb + (size_t)sb * 256 + q * 8);
        uint4 vc = *(const uint4*)(xpb + (size_t)sc * 256 + q * 8);
        uint4 vd = *(const uint4*)(xpb + (size_t)sd * 256 + q * 8);
        edge(sa, va); edge(sb, vb); edge(sc, vc); edge(sd, vd);
    }
    if (e + 3 < end) {
        int sa = csr_src[e + half];
        int sb = csr_src[e + 2 + half];
        uint4 va = *(const uint4*)(xpb + (size_t)sa * 256 + q * 8);
        uint4 vb = *(const uint4*)(xpb + (size_t)sb * 256 + q * 8);
        edge(sa, va); edge(sb, vb);
        e += 4;
    }
    if (e + 1 < end) {
        int sa = csr_src[e + half];
        uint4 va = *(const uint4*)(xpb + (size_t)sa * 256 + q * 8);
        edge(sa, va);
        e += 2;
    }
    if (e < end && half == 0) {
        int sa = csr_src[e];
        uint4 va = *(const uint4*)(xpb + (size_t)sa * 256 + q * 8);
        edge(sa, va);
    }

    // combine the two halves
#pragma unroll
    for (int j = 0; j < 8; j++) acc[j] += __shfl_xor(acc[j], 32, 64);
    den += __shfl_xor(den, 32, 64);

    float dinv = 1.f / (den + 1e-16f);
    float4 b0 = *(const float4*)(b1 + q * 8);
    float4 b4 = *(const float4*)(b1 + q * 8 + 4);
    float o0 = fmaxf(acc[0] * dinv + b0.x, 0.f);
    float o1 = fmaxf(acc[1] * dinv + b0.y, 0.f);
    float o2 = fmaxf(acc[2] * dinv + b0.z, 0.f);
    float o3 = fmaxf(acc[3] * dinv + b0.w, 0.f);
    float o4 = fmaxf(acc[4] * dinv + b4.x, 0.f);
    float o5 = fmaxf(acc[5] * dinv + b4.y, 0.f);
    float o6 = fmaxf(acc[6] * dinv + b4.z, 0.f);
    float o7 = fmaxf(acc[7] * dinv + b4.w, 0.f);
    if (half == 0) {
        uint4 Hv;
        Hv.x = (unsigned)f2bf(o0) | ((unsigned)f2bf(o1) << 16);
        Hv.y = (unsigned)f2bf(o2) | ((unsigned)f2bf(o3) << 16);
        Hv.z = (unsigned)f2bf(o4) | ((unsigned)f2bf(o5) << 16);
        Hv.w = (unsigned)f2bf(o6) | ((unsigned)f2bf(o7) << 16);
        *(uint4*)(h1h + (size_t)n * 256 + q * 8) = Hv;
    }
}

// gather layer 2 (1 head, C=64): 1 wave/node, 4 edge-groups of 16 lanes,
// lane q=lane&15 owns 4 cols (8B). r10 geometry + 4-deep ILP (r14).
// Fused uv = (h2+b2) . Wc halves.
__global__ __launch_bounds__(256) void k_gather2(const unsigned short* __restrict__ xp2b,
                                                 const float* __restrict__ as, const float* __restrict__ ad,
                                                 const int* __restrict__ rowptr, const int* __restrict__ csr_src,
                                                 const float* __restrict__ b2, const float* __restrict__ Wc,
                                                 float* __restrict__ uv, int M) {
    int wv = threadIdx.x >> 6, lane = threadIdx.x & 63;
    int n = blockIdx.x * 4 + wv;
    if (n >= M) return;
    int g = lane >> 4, q = lane & 15;
    float adv = ad[n];
    int start = rowptr[n], end = rowptr[n + 1];
    float acc0[4] = {0.f, 0.f, 0.f, 0.f}, acc1[4] = {0.f, 0.f, 0.f, 0.f};
    float acc2[4] = {0.f, 0.f, 0.f, 0.f}, acc3[4] = {0.f, 0.f, 0.f, 0.f};
    float den0 = 0.f, den1 = 0.f, den2 = 0.f, den3 = 0.f;
    int e = start;
    // 16 edges/iter: each group handles e+g, e+4+g, e+8+g, e+12+g (4 in flight)
    for (; e + 15 < end; e += 16) {
        int s0 = csr_src[e + g];
        int s1 = csr_src[e + 4 + g];
        int s2 = csr_src[e + 8 + g];
        int s3 = csr_src[e + 12 + g];
        uint2 v0 = *(const uint2*)(xp2b + (size_t)s0 * 64 + q * 4);
        uint2 v1 = *(const uint2*)(xp2b + (size_t)s1 * 64 + q * 4);
        uint2 v2 = *(const uint2*)(xp2b + (size_t)s2 * 64 + q * 4);
        uint2 v3 = *(const uint2*)(xp2b + (size_t)s3 * 64 + q * 4);
        float p0 = __expf(lrelu(as[s0] + adv));
        float p1 = __expf(lrelu(as[s1] + adv));
        float p2 = __expf(lrelu(as[s2] + adv));
        float p3 = __expf(lrelu(as[s3] + adv));
        den0 += p0; den1 += p1; den2 += p2; den3 += p3;
        acc0[0] += p0 * bflo(v0.x); acc0[1] += p0 * bfhi(v0.x);
        acc0[2] += p0 * bflo(v0.y); acc0[3] += p0 * bfhi(v0.y);
        acc1[0] += p1 * bflo(v1.x); acc1[1] += p1 * bfhi(v1.x);
        acc1[2] += p1 * bflo(v1.y); acc1[3] += p1 * bfhi(v1.y);
        acc2[0] += p2 * bflo(v2.x); acc2[1] += p2 * bfhi(v2.x);
        acc2[2] += p2 * bflo(v2.y); acc2[3] += p2 * bfhi(v2.y);
        acc3[0] += p3 * bflo(v3.x); acc3[1] += p3 * bfhi(v3.x);
        acc3[2] += p3 * bflo(v3.y); acc3[3] += p3 * bfhi(v3.y);
    }
    // 8 edges/iter (2 in flight)
    for (; e + 7 < end; e += 8) {
        int s0 = csr_src[e + g];
        int s1 = csr_src[e + 4 + g];
        uint2 v0 = *(const uint2*)(xp2b + (size_t)s0 * 64 + q * 4);
        uint2 v1 = *(const uint2*)(xp2b + (size_t)s1 * 64 + q * 4);
        float p0 = __expf(lrelu(as[s0] + adv));
        float p1 = __expf(lrelu(as[s1] + adv));
        den0 += p0; den1 += p1;
        acc0[0] += p0 * bflo(v0.x); acc0[1] += p0 * bfhi(v0.x);
        acc0[2] += p0 * bflo(v0.y); acc0[3] += p0 * bfhi(v0.y);
        acc1[0] += p1 * bflo(v1.x); acc1[1] += p1 * bfhi(v1.x);
        acc1[2] += p1 * bflo(v1.y); acc1[3] += p1 * bfhi(v1.y);
    }
    // predicated 4-edge tail
    for (; e < end; e += 4) {
        int ee = e + g;
        bool ok = ee < end;
        int s = csr_src[ok ? ee : start];
        uint2 v = *(const uint2*)(xp2b + (size_t)s * 64 + q * 4);
        float pw = ok ? __expf(lrelu(as[s] + adv)) : 0.f;
        den0 += pw;
        acc0[0] += pw * bflo(v.x); acc0[1] += pw * bfhi(v.x);
        acc0[2] += pw * bflo(v.y); acc0[3] += pw * bfhi(v.y);
    }
    float acc[4];
#pragma unroll
    for (int j = 0; j < 4; j++) {
        acc[j] = (acc0[j] + acc1[j]) + (acc2[j] + acc3[j]);
        acc[j] += __shfl_xor(acc[j], 16, 64);
        acc[j] += __shfl_xor(acc[j], 32, 64);
    }
    float den = (den0 + den1) + (den2 + den3);
    den += __shfl_xor(den, 16, 64);
    den += __shfl_xor(den, 32, 64);
    float dinv = 1.f / (den + 1e-16f);
    float pr[8] = {0.f, 0.f, 0.f, 0.f, 0.f, 0.f, 0.f, 0.f};
#pragma unroll
    for (int j = 0; j < 4; j++) {
        int c = q * 4 + j;
        float val = acc[j] * dinv + b2[c];
#pragma unroll
        for (int k = 0; k < 4; k++) {
            pr[k]     += val * Wc[c * 4 + k];
            pr[4 + k] += val * Wc[(64 + c) * 4 + k];
        }
    }
#pragma unroll
    for (int off = 1; off <= 8; off <<= 1)
#pragma unroll
        for (int j = 0; j < 8; j++) pr[j] += __shfl_xor(pr[j], off, 64);
    if (lane == 0) {
        float4* o = (float4*)(uv + (size_t)n * 8);
        o[0] = make_float4(pr[0], pr[1], pr[2], pr[3]);
        o[1] = make_float4(pr[4], pr[5], pr[6], pr[7]);
    }
}

__global__ __launch_bounds__(256) void k_classify(const int* __restrict__ ei, const float* __restrict__ uv,
                                                  const float* __restrict__ bc, float* __restrict__ out, int E) {
    int e = blockIdx.x * 256 + threadIdx.x;
    if (e >= E) return;
    int r = ei[e];
    int c = ei[E + e];
    float4 u = *(const float4*)(uv + (size_t)r * 8);
    float4 v = *(const float4*)(uv + (size_t)c * 8 + 4);
    float4 o;
    o.x = u.x + v.x + bc[0];
    o.y = u.y + v.y + bc[1];
    o.z = u.z + v.z + bc[2];
    o.w = u.w + v.w + bc[3];
    *(float4*)(out + (size_t)e * 4) = o;
}

// ---------------------------------------------------------------------------

extern "C" void kernel_launch(void* const* d_in, const int* in_sizes, int n_in,
                              void* d_out, int out_size, void* d_ws, size_t ws_size,
                              hipStream_t stream) {
    const float* x    = (const float*)d_in[0];
    const int*   ei   = (const int*)d_in[1];
    // d_in[2] = w (edge weights) ignored by reference
    const float* W1   = (const float*)d_in[3];
    const float* atS1 = (const float*)d_in[4];
    const float* atD1 = (const float*)d_in[5];
    const float* b1   = (const float*)d_in[6];
    const float* W2   = (const float*)d_in[7];
    const float* atS2 = (const float*)d_in[8];
    const float* atD2 = (const float*)d_in[9];
    const float* b2   = (const float*)d_in[10];
    const float* Wc   = (const float*)d_in[11];
    const float* bc   = (const float*)d_in[12];
    float* out = (float*)d_out;

    const int Nn = in_sizes[0] / 256;   // nodes
    const int E = in_sizes[1] / 2;
    const int Etot = E + Nn;
    const int NB = (Nn + 255) / 256;    // scan blocks

    char* w = (char*)d_ws;
    size_t off = 0;
    auto alloc = [&](size_t b) { size_t o = off; off = (o + b + 255) & ~(size_t)255; return o; };
    size_t oXH  = alloc((size_t)Nn * 256 * 2);   // x bf16; later h1h
    size_t oXPB = alloc((size_t)Nn * 256 * 2);   // xp bf16; later xp2b|uv
    size_t oAS1 = alloc((size_t)Nn * 4 * 4);
    size_t oAD1 = alloc((size_t)Nn * 4 * 4);
    size_t oDC  = alloc((size_t)Nn * 2 * 4);     // deg | cur adjacent -> 1 memset
    size_t oRP  = alloc((size_t)(Nn + 1) * 4);
    size_t oCSR = alloc((size_t)Etot * 4);
    size_t oW1H = alloc((size_t)256 * 256 * 2);
    size_t oW1L = alloc((size_t)256 * 256 * 2);
    size_t oW2H = alloc((size_t)256 * 64 * 2);
    size_t oW2L = alloc((size_t)256 * 64 * 2);
    size_t oBS  = alloc((size_t)NB * 4);
    (void)ws_size;

    unsigned short* xh   = (unsigned short*)(w + oXH);
    unsigned short* h1h  = (unsigned short*)(w + oXH);   // alias: xh dead after gemm1
    unsigned short* xpb  = (unsigned short*)(w + oXPB);
    unsigned short* xp2b = (unsigned short*)(w + oXPB);  // alias: xpb dead after gather1
    float* uv  = (float*)(w + oXPB + (size_t)Nn * 64 * 2 + 256);
    uv = (float*)(((uintptr_t)uv + 255) & ~(uintptr_t)255);
    float* as1 = (float*)(w + oAS1);
    float* ad1 = (float*)(w + oAD1);
    float* as2 = (float*)(w + oAS1);                     // alias: as1 dead after gather1
    float* ad2 = (float*)(w + oAD1);
    int* deg    = (int*)(w + oDC);
    int* cur    = (int*)(w + oDC) + Nn;
    int* rowptr = (int*)(w + oRP);
    int* csr    = (int*)(w + oCSR);
    int* bsum   = (int*)(w + oBS);
    unsigned short* W1hT = (unsigned short*)(w + oW1H);
    unsigned short* W1lT = (unsigned short*)(w + oW1L);
    unsigned short* W2hT = (unsigned short*)(w + oW2H);
    unsigned short* W2lT = (unsigned short*)(w + oW2L);

    // zero deg+cur in one shot (adjacent)
    hipMemsetAsync(deg, 0, (size_t)Nn * 2 * 4, stream);

    // merged prep: hist + pack x + pack W (independent jobs, one dispatch)
    k_prep<<<2368, 256, 0, stream>>>(ei, deg, E, x, xh, (long)Nn * 64,
                                     W1, W2, W1hT, W1lT, W2hT, W2lT);

    // CSR scan (bsum -> rowptr-with-inline-bscan) + scatter
    k_bsum<<<NB, 256, 0, stream>>>(deg, bsum, Nn);
    k_rowptr<<<NB, 256, 0, stream>>>(deg, bsum, rowptr, NB, Nn);
    k_scatter<<<(Etot + 255) / 256, 256, 0, stream>>>(ei, rowptr, cur, csr, E, Nn);

    // Layer 1: 128x128 tile (WGM=2, WGN=2), grid.y = 2; attn fused
    {
        dim3 g((Nn + 127) / 128, 2);
        k_gemm_lds<2, 2><<<g, 256, 0, stream>>>(xh, W1hT, W1lT, xpb, Nn, 256, 256,
                                                atS1, atD1, as1, ad1, 4);
    }
    k_gather1<<<(Nn + 3) / 4, 256, 0, stream>>>(xpb, as1, ad1, rowptr, csr, b1, h1h, Nn);

    // Layer 2: 256x64 tile (WGM=4, WGN=1), grid.y = 1; attn fused
    {
        dim3 g((Nn + 255) / 256, 1);
        k_gemm_lds<4, 1><<<g, 256, 0, stream>>>(h1h, W2hT, W2lT, xp2b, Nn, 64, 256,
                                                atS2, atD2, as2, ad2, 1);
    }
    k_gather2<<<(Nn + 3) / 4, 256, 0, stream>>>(xp2b, as2, ad2, rowptr, csr, b2, Wc, uv, Nn);

    // Edge classifier
    k_classify<<<(E + 255) / 256, 256, 0, stream>>>(ei, uv, bc, out, E);
}